// Round 1
// 1284.388 us; speedup vs baseline: 3.4232x; 3.4232x over previous
//
#include <hip/hip_runtime.h>
#include <cstdint>
#include <cstddef>

#define DD 768
#define SS 128
#define NNODE 12288            // 3*B*S
#define NBS 4096               // B*S
#define NBSD 3145728           // B*S*D (per-chunk elements)
#define TOTAL_ND 9437184ULL    // NNODE*DD == out_size (fp32 elements)

typedef __attribute__((ext_vector_type(4))) float f32x4;
typedef __attribute__((ext_vector_type(8))) short bf16x8;

__device__ __forceinline__ float b2f(uint16_t u) {
    union { uint32_t i; float f; } x; x.i = ((uint32_t)u) << 16; return x.f;
}
__device__ __forceinline__ uint16_t f2b(float f) {
    uint32_t x = __float_as_uint(f);
    return (uint16_t)((x + 0x7FFFu + ((x >> 16) & 1u)) >> 16);
}
__device__ __forceinline__ float loadf(const void* p, size_t i, int isf32) {
    return isf32 ? ((const float*)p)[i] : b2f(((const uint16_t*)p)[i]);
}
// feats[n][d] = src_{d%3}[n*256 + d/3]
__device__ __forceinline__ float featAt(const void* hc, const void* hd, const void* hs,
                                        int n, int d, int isf) {
    int w = d % 3;
    size_t u = (size_t)n * 256 + (size_t)(d / 3);
    const void* p = (w == 0) ? hc : (w == 1) ? hd : hs;
    return loadf(p, u, isf);
}

// async 16B global->LDS (linear dest: wave-uniform base + lane*16)
__device__ __forceinline__ void gload16(const uint16_t* g, uint16_t* l) {
    __builtin_amdgcn_global_load_lds(
        (__attribute__((address_space(1))) uint32_t*)(uintptr_t)g,
        (__attribute__((address_space(3))) uint32_t*)l, 16, 0, 0);
}

// ---------- diag beacon (fp32 out) ----------
__global__ void k_diag(float* out, float code) {
    if (threadIdx.x == 0 && blockIdx.x == 0) out[0] = code;
}

// ---------- dtype probe (fp32 vs bf16 input arrays) ----------
__global__ void k_probe(const void* hf, int* flag) {
    if (threadIdx.x == 0 && blockIdx.x == 0) {
        const uint32_t* w = (const uint32_t*)hf;
        int bad = 0;
        for (int k = 0; k < 64; k++) {
            uint16_t lo = (uint16_t)(w[k] & 0xFFFFu);
            int e = (lo >> 7) & 0xFF;
            if (e < 100 || e > 140) bad++;
        }
        flag[0] = (bad > 24) ? 1 : 0;
    }
}

// ---------- feats build (bf16 store; GEMM-A for xw) ----------
__global__ __launch_bounds__(256) void k_build_feats(
    const void* __restrict__ hc, const void* __restrict__ hd,
    const void* __restrict__ hs, uint16_t* __restrict__ feats,
    const int* __restrict__ flag) {
    int u = blockIdx.x * 256 + threadIdx.x;
    int isf = flag[0];
    if (u < NBSD) {
        feats[3 * (size_t)u + 0] = f2b(loadf(hc, u, isf));
        feats[3 * (size_t)u + 1] = f2b(loadf(hd, u, isf));
        feats[3 * (size_t)u + 2] = f2b(loadf(hs, u, isf));
    }
}

// ---------- exact fp32 node norms (first 128 nodes) ----------
__global__ void k_nrm2(const void* hc, const void* hd, const void* hs,
                       float* nrm, const int* flag) {
    int n = threadIdx.x;   // <<<1,128>>>
    int isf = flag[0];
    float s = 0.f;
    for (int d = 0; d < DD; d++) { float v = featAt(hc, hd, hs, n, d, isf); s += v * v; }
    nrm[n] = fmaxf(sqrtf(s), 1e-8f);
}

// ---------- exact fp32 cosine sims ----------
__global__ __launch_bounds__(256) void k_sim2(const void* hc, const void* hd, const void* hs,
                                              const float* nrm, float* simb, const int* flag) {
    int e = blockIdx.x * 256 + threadIdx.x;   // <<<64,256>>>
    if (e >= SS * SS) return;
    int i = e >> 7, j = e & 127;
    int isf = flag[0];
    float s = 0.f;
    for (int d = 0; d < DD; d++)
        s += featAt(hc, hd, hs, i, d, isf) * featAt(hc, hd, hs, j, d, isf);
    simb[e] = s / (nrm[i] * nrm[j]);
}

// ---------- min/max over 16384 sims ----------
__global__ __launch_bounds__(256) void k_minmax(const float* __restrict__ simb,
                                                float* __restrict__ mnmx) {
    int tid = threadIdx.x;
    float mn = 3.4e38f, mx = -3.4e38f;
    for (int e = tid; e < SS * SS; e += 256) {
        float v = simb[e]; mn = fminf(mn, v); mx = fmaxf(mx, v);
    }
    __shared__ float rmn[256], rmx[256];
    rmn[tid] = mn; rmx[tid] = mx; __syncthreads();
    for (int o = 128; o > 0; o >>= 1) {
        if (tid < o) { rmn[tid] = fminf(rmn[tid], rmn[tid + o]); rmx[tid] = fmaxf(rmx[tid], rmx[tid + o]); }
        __syncthreads();
    }
    if (tid == 0) { mnmx[0] = rmn[0]; mnmx[1] = rmx[0]; }
}

// ---------- normalize sims in place, deg/dinv ----------
__global__ __launch_bounds__(128) void k_deg(float* __restrict__ simb,
                                             const float* __restrict__ mnmx,
                                             float* __restrict__ deg,
                                             float* __restrict__ dinv) {
    int j = blockIdx.x, i = threadIdx.x;
    float mn = mnmx[0], inv = 1.f / (mnmx[1] - mnmx[0]);
    float s = (simb[i * SS + j] - mn) * inv;
    simb[i * SS + j] = s;
    __shared__ float red[128];
    red[i] = s; __syncthreads();
    for (int o = 64; o > 0; o >>= 1) { if (i < o) red[i] += red[i + o]; __syncthreads(); }
    if (i == 0) { float d = red[0] + 1.f; deg[j] = d; dinv[j] = rsqrtf(d); }
}

// ---------- GCN neighbor aggregate (j<128), grid (SS,3) ----------
__global__ __launch_bounds__(256) void k_agg(const float* __restrict__ simb,
                                             const float* __restrict__ dinv,
                                             const uint16_t* __restrict__ xw,
                                             float* __restrict__ aggb) {
    int j = blockIdx.x;
    int d = blockIdx.y * 256 + threadIdx.x;
    __shared__ float w[SS];
    if (threadIdx.x < SS) w[threadIdx.x] = dinv[threadIdx.x] * simb[threadIdx.x * SS + j] * dinv[j];
    __syncthreads();
    float s = 0.f;
    #pragma unroll 8
    for (int i = 0; i < SS; i++) s += w[i] * b2f(xw[(size_t)i * DD + d]);
    aggb[(size_t)j * DD + d] = s;
}

// ---------- GCN combine in place (bf16 state) ----------
__global__ __launch_bounds__(256) void k_gcn_combine(uint16_t* __restrict__ xw,
                                                     const float* __restrict__ aggb,
                                                     const float* __restrict__ deg,
                                                     const void* __restrict__ gcnb,
                                                     const int* __restrict__ flag) {
    int d = blockIdx.x * 256 + threadIdx.x;
    int n = blockIdx.y;
    size_t t = (size_t)n * DD + d;
    float v = b2f(xw[t]);
    if (n < SS) v = v / deg[n] + aggb[t];
    v += loadf(gcnb, d, flag[0]);
    xw[t] = f2b(fmaxf(v, 0.f));
}

// ---------- colsum over first 128 rows ----------
__global__ __launch_bounds__(256) void k_colsum(const uint16_t* __restrict__ x,
                                                float* __restrict__ svec) {
    int d = blockIdx.x * 256 + threadIdx.x;
    if (d < DD) {
        float s = 0.f;
        for (int i = 0; i < SS; i++) s += b2f(x[(size_t)i * DD + d]);
        svec[d] = s;
    }
}

// ---------- mvec = svec @ ggc_W[l] ----------
__global__ __launch_bounds__(256) void k_matvec(const float* __restrict__ svec,
                                                const void* __restrict__ Wg, size_t ofs,
                                                float* __restrict__ mvec,
                                                const int* __restrict__ flag) {
    int k = blockIdx.x * 256 + threadIdx.x;
    int isf = flag[0];
    if (k < DD) {
        float s = 0.f;
        for (int d = 0; d < DD; d++) s += svec[d] * loadf(Wg, ofs + (size_t)d * DD + k, isf);
        mvec[k] = s;
    }
}

// ---------- giE = mvec @ wih.T + bih ----------
__global__ __launch_bounds__(256) void k_rowdot(const float* __restrict__ mvec,
                                                const void* __restrict__ wih,
                                                const void* __restrict__ bih,
                                                float* __restrict__ giE,
                                                const int* __restrict__ flag) {
    int rr = blockIdx.x, tid = threadIdx.x;
    int isf = flag[0];
    float s = 0.f;
    for (int k = tid; k < DD; k += 256) s += mvec[k] * loadf(wih, (size_t)rr * DD + k, isf);
    __shared__ float red[256];
    red[tid] = s; __syncthreads();
    for (int o = 128; o > 0; o >>= 1) { if (tid < o) red[tid] += red[tid + o]; __syncthreads(); }
    if (tid == 0) giE[rr] = red[0] + loadf(bih, rr, isf);
}

// ---------- y = h_feature + relu(x_g), bf16 store ----------
__global__ __launch_bounds__(256) void k_build_y(const void* __restrict__ hf,
                                                 const uint16_t* __restrict__ xg,
                                                 uint16_t* __restrict__ y,
                                                 const int* __restrict__ flag) {
    int t = blockIdx.x * 256 + threadIdx.x;
    int isf = flag[0];
    if (t < NBSD) y[t] = f2b(loadf(hf, t, isf) + fmaxf(b2f(xg[t]), 0.f));
}

// ---------- LayerNorm -> FLOAT32 output ----------
__global__ __launch_bounds__(256) void k_ln(const uint16_t* __restrict__ tin,
                                            const void* __restrict__ gw,
                                            const void* __restrict__ bw,
                                            float* __restrict__ out,
                                            const int* __restrict__ flag) {
    int m = blockIdx.x, tid = threadIdx.x;
    int isf = flag[0];
    float v0 = b2f(tin[(size_t)m * DD + tid]);
    float v1 = b2f(tin[(size_t)m * DD + tid + 256]);
    float v2 = b2f(tin[(size_t)m * DD + tid + 512]);
    __shared__ float red[256];
    red[tid] = v0 + v1 + v2; __syncthreads();
    for (int o = 128; o > 0; o >>= 1) { if (tid < o) red[tid] += red[tid + o]; __syncthreads(); }
    float mu = red[0] * (1.f / 768.f);
    __syncthreads();
    float d0 = v0 - mu, d1 = v1 - mu, d2 = v2 - mu;
    red[tid] = d0 * d0 + d1 * d1 + d2 * d2; __syncthreads();
    for (int o = 128; o > 0; o >>= 1) { if (tid < o) red[tid] += red[tid + o]; __syncthreads(); }
    float rstd = rsqrtf(red[0] * (1.f / 768.f) + 1e-5f);
    out[(size_t)m * DD + tid]       = d0 * rstd * loadf(gw, tid, isf)       + loadf(bw, tid, isf);
    out[(size_t)m * DD + tid + 256] = d1 * rstd * loadf(gw, tid + 256, isf) + loadf(bw, tid + 256, isf);
    out[(size_t)m * DD + tid + 512] = d2 * rstd * loadf(gw, tid + 512, isf) + loadf(bw, tid + 512, isf);
}

// ---------- weight convert: hi/lo bf16 split, elementwise ----------
__global__ __launch_bounds__(256) void k_cvt2(const void* __restrict__ src,
                                              uint16_t* __restrict__ dh,
                                              uint16_t* __restrict__ dl, int n,
                                              const int* __restrict__ flag) {
    int t = blockIdx.x * 256 + threadIdx.x;
    if (t < n) {
        float v = loadf(src, t, flag[0]);
        uint16_t h = f2b(v);
        dh[t] = h;
        dl[t] = f2b(v - b2f(h));
    }
}

// ---------- weight convert: transpose + hi/lo split (768x768) ----------
// dh/dl[n][k] = split(src[k][n])
__global__ __launch_bounds__(256) void k_cvtT(const void* __restrict__ src,
                                              uint16_t* __restrict__ dh,
                                              uint16_t* __restrict__ dl,
                                              const int* __restrict__ flag) {
    __shared__ float tile[64][65];
    int isf = flag[0];
    int k0 = blockIdx.x * 64, n0 = blockIdx.y * 64;
    for (int t = threadIdx.x; t < 4096; t += 256) {
        int r = t >> 6, c = t & 63;
        tile[r][c] = loadf(src, (size_t)(k0 + r) * DD + n0 + c, isf);
    }
    __syncthreads();
    for (int t = threadIdx.x; t < 4096; t += 256) {
        int r = t >> 6, c = t & 63;
        float v = tile[c][r];
        uint16_t h = f2b(v);
        size_t o = (size_t)(n0 + r) * DD + k0 + c;
        dh[o] = h;
        dl[o] = f2b(v - b2f(h));
    }
}

// =============== MFMA GEMM: C[M,768] = A[M,768] @ BT^T, bf16 ===============
// BT layout: [768][768] row = output col n, col = k.  BTl = bf16 residual
// (second K-pass only when inputs are fp32).  128x128 tile, BK=32, 4 waves.
// LDS swizzle: physical 16B-group g_phys = g_log ^ ((row>>1)&3), applied to
// the GLOBAL source during global_load_lds staging and to the ds_read address.
enum { EPI_NONE = 0, EPI_BIAS_RELU = 3, EPI_BIAS = 4 };

template<int EPI>
__global__ __launch_bounds__(256)
void k_mgemm(const uint16_t* __restrict__ A,
             const uint16_t* __restrict__ BTh, const uint16_t* __restrict__ BTl,
             const void* __restrict__ bias, uint16_t* __restrict__ C,
             const int* __restrict__ flag) {
    __shared__ __align__(16) uint16_t As[128 * 32];
    __shared__ __align__(16) uint16_t Bs[128 * 32];
    const int isf = flag[0];
    const int tid = threadIdx.x, lane = tid & 63, wid = tid >> 6;
    const int wr = wid >> 1, wc = wid & 1;                 // 2x2 waves, 64x64 each
    const int m0 = blockIdx.y * 128, n0 = blockIdx.x * 128;

    f32x4 zero = {0.f, 0.f, 0.f, 0.f};
    f32x4 acc[4][4];
    #pragma unroll
    for (int i = 0; i < 4; i++)
        #pragma unroll
        for (int j = 0; j < 4; j++) acc[i][j] = zero;

    const int halves = isf ? 2 : 1;
    for (int h = 0; h < halves; h++) {
        const uint16_t* BT = h ? BTl : BTh;
        for (int k0 = 0; k0 < DD; k0 += 32) {
            #pragma unroll
            for (int rd = 0; rd < 2; rd++) {
                int c = rd * 256 + tid;
                int r = c >> 2, g = c & 3;
                int gl = g ^ ((r >> 1) & 3);               // pre-swizzled source
                uint16_t* dstA = As + (size_t)(rd * 256 + wid * 64) * 8;
                uint16_t* dstB = Bs + (size_t)(rd * 256 + wid * 64) * 8;
                gload16(A  + (size_t)(m0 + r) * DD + k0 + gl * 8, dstA);
                gload16(BT + (size_t)(n0 + r) * DD + k0 + gl * 8, dstB);
            }
            __syncthreads();
            bf16x8 af[4], bfv[4];
            #pragma unroll
            for (int i = 0; i < 4; i++) {
                int r = wr * 64 + i * 16 + (lane & 15);
                int g = (lane >> 4) ^ ((r >> 1) & 3);
                af[i] = *(const bf16x8*)(As + r * 32 + g * 8);
            }
            #pragma unroll
            for (int j = 0; j < 4; j++) {
                int r = wc * 64 + j * 16 + (lane & 15);
                int g = (lane >> 4) ^ ((r >> 1) & 3);
                bfv[j] = *(const bf16x8*)(Bs + r * 32 + g * 8);
            }
            #pragma unroll
            for (int i = 0; i < 4; i++)
                #pragma unroll
                for (int j = 0; j < 4; j++)
                    acc[i][j] = __builtin_amdgcn_mfma_f32_16x16x32_bf16(af[i], bfv[j], acc[i][j], 0, 0, 0);
            __syncthreads();
        }
    }
    // D layout: col = lane&15, row = (lane>>4)*4 + q (verified m89/m91)
    #pragma unroll
    for (int i = 0; i < 4; i++) {
        #pragma unroll
        for (int j = 0; j < 4; j++) {
            int n = n0 + wc * 64 + j * 16 + (lane & 15);
            int mb = m0 + wr * 64 + i * 16 + ((lane >> 4) << 2);
            float bv = 0.f;
            if (EPI != EPI_NONE) bv = loadf(bias, n, isf);
            #pragma unroll
            for (int q = 0; q < 4; q++) {
                float v = acc[i][j][q];
                if (EPI == EPI_BIAS_RELU) v = fmaxf(v + bv, 0.f);
                else if (EPI == EPI_BIAS) v = v + bv;
                C[(size_t)(mb + q) * DD + n] = f2b(v);
            }
        }
    }
}

// =============== MFMA fused GRU layer: 3-gate GEMM + GRU cell ===============
// Xn[12288,768]: gates gh = X @ whh.T via whh bf16 hi/lo [2304][768] (BT form).
// 64x64 block (per gate), 4 waves of 32x32, grid (12,192).
__global__ __launch_bounds__(256)
void k_grum(const uint16_t* __restrict__ X,
            const uint16_t* __restrict__ Wh, const uint16_t* __restrict__ Wl,
            const void* __restrict__ bih, const void* __restrict__ bhh,
            const float* __restrict__ giE, uint16_t* __restrict__ Xn,
            const int* __restrict__ flag) {
    __shared__ __align__(16) uint16_t As[64 * 32];
    __shared__ __align__(16) uint16_t Bs[3][64 * 32];
    const int isf = flag[0];
    const int tid = threadIdx.x, lane = tid & 63, wid = tid >> 6;
    const int wr = wid >> 1, wc = wid & 1;                 // 2x2 waves, 32x32 each
    const int n0 = blockIdx.x * 64, m0 = blockIdx.y * 64;

    f32x4 zero = {0.f, 0.f, 0.f, 0.f};
    f32x4 acc[3][2][2];
    #pragma unroll
    for (int gg = 0; gg < 3; gg++)
        #pragma unroll
        for (int i = 0; i < 2; i++)
            #pragma unroll
            for (int j = 0; j < 2; j++) acc[gg][i][j] = zero;

    const int sr = tid >> 2, sg = tid & 3;
    const int sgl = sg ^ ((sr >> 1) & 3);

    const int halves = isf ? 2 : 1;
    for (int h = 0; h < halves; h++) {
        const uint16_t* W = h ? Wl : Wh;
        for (int k0 = 0; k0 < DD; k0 += 32) {
            uint16_t* dstA = As + (size_t)(wid * 64) * 8;
            gload16(X + (size_t)(m0 + sr) * DD + k0 + sgl * 8, dstA);
            #pragma unroll
            for (int gg = 0; gg < 3; gg++) {
                uint16_t* dstB = Bs[gg] + (size_t)(wid * 64) * 8;
                gload16(W + (size_t)(gg * DD + n0 + sr) * DD + k0 + sgl * 8, dstB);
            }
            __syncthreads();
            bf16x8 af[2];
            #pragma unroll
            for (int i = 0; i < 2; i++) {
                int r = wr * 32 + i * 16 + (lane & 15);
                int g = (lane >> 4) ^ ((r >> 1) & 3);
                af[i] = *(const bf16x8*)(As + r * 32 + g * 8);
            }
            #pragma unroll
            for (int gg = 0; gg < 3; gg++) {
                #pragma unroll
                for (int j = 0; j < 2; j++) {
                    int r = wc * 32 + j * 16 + (lane & 15);
                    int g = (lane >> 4) ^ ((r >> 1) & 3);
                    bf16x8 bv = *(const bf16x8*)(Bs[gg] + r * 32 + g * 8);
                    #pragma unroll
                    for (int i = 0; i < 2; i++)
                        acc[gg][i][j] = __builtin_amdgcn_mfma_f32_16x16x32_bf16(af[i], bv, acc[gg][i][j], 0, 0, 0);
                }
            }
            __syncthreads();
        }
    }
    // epilogue: full GRU cell pointwise
    #pragma unroll
    for (int i = 0; i < 2; i++) {
        #pragma unroll
        for (int j = 0; j < 2; j++) {
            int n = n0 + wc * 32 + j * 16 + (lane & 15);
            int mb = m0 + wr * 32 + i * 16 + ((lane >> 4) << 2);
            float bh0 = loadf(bhh, n, isf);
            float bh1 = loadf(bhh, DD + n, isf);
            float bh2 = loadf(bhh, 2 * DD + n, isf);
            float gE0 = giE[n], gE1 = giE[DD + n], gE2 = giE[2 * DD + n];
            float bi0 = loadf(bih, n, isf);
            float bi1 = loadf(bih, DD + n, isf);
            float bi2 = loadf(bih, 2 * DD + n, isf);
            #pragma unroll
            for (int q = 0; q < 4; q++) {
                int m = mb + q;
                bool msg = (m < SS);
                float gr = msg ? gE0 : bi0;
                float gz = msg ? gE1 : bi1;
                float gn = msg ? gE2 : bi2;
                float rg = 1.f / (1.f + expf(-(acc[0][i][j][q] + bh0 + gr)));
                float zg = 1.f / (1.f + expf(-(acc[1][i][j][q] + bh1 + gz)));
                float hn = acc[2][i][j][q] + bh2;
                float nn = tanhf(gn + rg * hn);
                float xo = b2f(X[(size_t)m * DD + n]);
                Xn[(size_t)m * DD + n] = f2b((1.f - zg) * nn + zg * xo);
            }
        }
    }
}

// ============================== driver ==============================
extern "C" void kernel_launch(void* const* d_in, const int* in_sizes, int n_in,
                              void* d_out, int out_size, void* d_ws, size_t ws_size,
                              hipStream_t stream) {
    float* OUTF = (float*)d_out;            // FINAL output: fp32
    uint16_t* OB = (uint16_t*)d_out;        // first 18.9MB of d_out reused as bf16 trunk scratch

    static const int expect[29] = {
        3145728,3145728,3145728,3145728, 589824,768, 1179648, 1769472,1769472, 2304,2304,
        589824,768,589824,768,768,768,
        589824,768,589824,768,768,768,
        589824,768,589824,768,768,768 };
    int bad = -1;
    if (n_in != 29) bad = 90;
    else { for (int i = 0; i < 29; i++) if (in_sizes[i] != expect[i]) { bad = i; break; } }
    if (bad < 0 && out_size != (int)TOTAL_ND) bad = 91;
    if (bad < 0 && ws_size < 33ull * 1024 * 1024) bad = 92;
    if (bad >= 0) {
        k_diag<<<1, 64, 0, stream>>>(OUTF, 10000.f + 100.f * (float)bad);
        return;
    }

    // ws layout: fp32 scratch (476KB) | W0 bf16 [12288,768] | WH bf16 3.1M | WT bf16 3.1M
    float* fbase = (float*)d_ws;
    float* simb = fbase;                 // 16384
    float* nrm  = simb + 16384;          // 128
    float* mnmx = nrm + 128;             // 2
    float* deg  = mnmx + 2;              // 128
    float* dinv = deg + 128;             // 128
    float* aggb = dinv + 128;            // 98304
    float* svec = aggb + 98304;          // 768
    float* mvec = svec + 768;            // 768
    float* giE  = mvec + 768;            // 2304
    int*   flag = (int*)(giE + 2304);    // 1
    uint16_t* W0 = (uint16_t*)(fbase + 119040);   // 9,437,184 bf16
    uint16_t* WH = W0 + TOTAL_ND;                 // 3,145,728 bf16 slots
    uint16_t* WT = WH + NBSD;                     // 3,145,728 bf16 slots

    // per-head W1/W2 hi+lo bf16 live in the TAIL of d_out (chunk 2, dead until
    // head-2's final LN which runs after the last read of them)
    uint16_t* W1h = (uint16_t*)(OUTF + (TOTAL_ND - 1179648ULL));  // 4 x 589824 bf16
    uint16_t* W1l = W1h + 589824;
    uint16_t* W2h = W1l + 589824;
    uint16_t* W2l = W2h + 589824;

    const void* hf = d_in[0];
    const void* hc = d_in[1];
    const void* hd = d_in[2];
    const void* hs = d_in[3];

    k_probe<<<1, 64, 0, stream>>>(hf, flag);

    // ---- GCN front-end ----
    k_build_feats<<<NBSD / 256, 256, 0, stream>>>(hc, hd, hs, W0, flag);
    k_nrm2<<<1, 128, 0, stream>>>(hc, hd, hs, nrm, flag);
    k_sim2<<<64, 256, 0, stream>>>(hc, hd, hs, nrm, simb, flag);
    k_minmax<<<1, 256, 0, stream>>>(simb, mnmx);
    k_deg<<<SS, SS, 0, stream>>>(simb, mnmx, deg, dinv);
    // gcn_W^T hi/lo into WH (free until heads)
    k_cvtT<<<dim3(12, 12), 256, 0, stream>>>(d_in[4], WH, WH + 589824, flag);
    k_mgemm<EPI_NONE><<<dim3(6, 96), 256, 0, stream>>>(W0, WH, WH + 589824, nullptr, OB, flag);
    k_agg<<<dim3(SS, 3), 256, 0, stream>>>(simb, dinv, OB, aggb);
    k_gcn_combine<<<dim3(3, NNODE), 256, 0, stream>>>(OB, aggb, deg, d_in[5], flag);

    // ---- GatedGraphConv: whh hi->WH, lo->WT (both free until heads) ----
    k_cvt2<<<6912, 256, 0, stream>>>(d_in[8], WH, WT, 1769472, flag);

    k_colsum<<<3, 256, 0, stream>>>(OB, svec);
    k_matvec<<<3, 256, 0, stream>>>(svec, d_in[6], 0, mvec, flag);
    k_rowdot<<<2304, 256, 0, stream>>>(mvec, d_in[7], d_in[9], giE, flag);
    k_grum<<<dim3(12, 192), 256, 0, stream>>>(OB, WH, WT, d_in[9], d_in[10], giE, W0, flag);

    k_colsum<<<3, 256, 0, stream>>>(W0, svec);
    k_matvec<<<3, 256, 0, stream>>>(svec, d_in[6], (size_t)DD * DD, mvec, flag);
    k_rowdot<<<2304, 256, 0, stream>>>(mvec, d_in[7], d_in[9], giE, flag);
    k_grum<<<dim3(12, 192), 256, 0, stream>>>(W0, WH, WT, d_in[9], d_in[10], giE, OB, flag);

    // ---- build ALL THREE y chunks first (reads OB before fp32 LN writes) ----
    for (int g = 0; g < 3; ++g)
        k_build_y<<<NBSD / 256, 256, 0, stream>>>(hf, OB + (size_t)g * NBSD,
                                                  W0 + (size_t)g * NBSD, flag);

    // ---- heads: y -> h1 -> t -> LN (fp32 to d_out) ----
    for (int g = 0; g < 3; ++g) {
        const void* W1 = d_in[11 + 6 * g];
        const void* b1 = d_in[12 + 6 * g];
        const void* W2 = d_in[13 + 6 * g];
        const void* b2 = d_in[14 + 6 * g];
        const void* gw = d_in[15 + 6 * g];
        const void* bw = d_in[16 + 6 * g];
        k_cvtT<<<dim3(12, 12), 256, 0, stream>>>(W1, W1h, W1l, flag);
        k_cvtT<<<dim3(12, 12), 256, 0, stream>>>(W2, W2h, W2l, flag);
        k_mgemm<EPI_BIAS_RELU><<<dim3(6, 32), 256, 0, stream>>>(W0 + (size_t)g * NBSD, W1h, W1l, b1, WH, flag);
        k_mgemm<EPI_BIAS><<<dim3(6, 32), 256, 0, stream>>>(WH, W2h, W2l, b2, WT, flag);
        k_ln<<<NBS, 256, 0, stream>>>(WT, gw, bw, OUTF + (size_t)g * NBSD, flag);
    }
}

// Round 2
// 979.653 us; speedup vs baseline: 4.4880x; 1.3111x over previous
//
#include <hip/hip_runtime.h>
#include <cstdint>
#include <cstddef>

#define DD 768
#define SS 128
#define NNODE 12288            // 3*B*S
#define NBS 4096               // B*S
#define NBSD 3145728           // B*S*D (per-chunk elements)
#define TOTAL_ND 9437184ULL    // NNODE*DD == out_size (fp32 elements)
#define WMAT 589824            // 768*768
#define WSLOT 1179648          // hi+lo pair of one 768x768 matrix (u16 elems)

typedef __attribute__((ext_vector_type(4))) float f32x4;
typedef __attribute__((ext_vector_type(8))) short bf16x8;
typedef __attribute__((ext_vector_type(4))) uint16_t u16x4;
typedef __attribute__((ext_vector_type(8))) uint16_t u16x8;
typedef __attribute__((ext_vector_type(2))) uint32_t u32x2;

__device__ __forceinline__ float b2f(uint16_t u) {
    union { uint32_t i; float f; } x; x.i = ((uint32_t)u) << 16; return x.f;
}
__device__ __forceinline__ uint16_t f2b(float f) {
    uint32_t x = __float_as_uint(f);
    return (uint16_t)((x + 0x7FFFu + ((x >> 16) & 1u)) >> 16);
}
__device__ __forceinline__ float loadf(const void* p, size_t i, int isf32) {
    return isf32 ? ((const float*)p)[i] : b2f(((const uint16_t*)p)[i]);
}
// feats[n][d] = src_{d%3}[n*256 + d/3]
__device__ __forceinline__ float featAt(const void* hc, const void* hd, const void* hs,
                                        int n, int d, int isf) {
    int w = d % 3;
    size_t u = (size_t)n * 256 + (size_t)(d / 3);
    const void* p = (w == 0) ? hc : (w == 1) ? hd : hs;
    return loadf(p, u, isf);
}
__device__ __forceinline__ uint32_t pk2(uint16_t a, uint16_t b) {
    return (uint32_t)a | ((uint32_t)b << 16);
}

// async 16B global->LDS (linear dest: wave-uniform base + lane*16)
__device__ __forceinline__ void gload16(const uint16_t* g, uint16_t* l) {
    __builtin_amdgcn_global_load_lds(
        (__attribute__((address_space(1))) uint32_t*)(uintptr_t)g,
        (__attribute__((address_space(3))) uint32_t*)l, 16, 0, 0);
}

// bijective XCD swizzle (m204 variant) applied to 2D grid
__device__ __forceinline__ void xcd_swz(int& bx, int& by, int gx, int gy) {
    int nwg = gx * gy;
    int id = bx + gx * by;
    int q = nwg >> 3, r = nwg & 7;
    int xcd = id & 7, rest = id >> 3;
    int sid = (xcd < r) ? (xcd * (q + 1) + rest) : (r * (q + 1) + (xcd - r) * q + rest);
    bx = sid % gx; by = sid / gx;
}

// ---------- diag beacon ----------
__global__ void k_diag(float* out, float code) {
    if (threadIdx.x == 0 && blockIdx.x == 0) out[0] = code;
}

// ---------- dtype probe ----------
__global__ void k_probe(const void* hf, int* flag) {
    if (threadIdx.x == 0 && blockIdx.x == 0) {
        const uint32_t* w = (const uint32_t*)hf;
        int bad = 0;
        for (int k = 0; k < 64; k++) {
            uint16_t lo = (uint16_t)(w[k] & 0xFFFFu);
            int e = (lo >> 7) & 0xFF;
            if (e < 100 || e > 140) bad++;
        }
        flag[0] = (bad > 24) ? 1 : 0;
    }
}

// ---------- feats build (vec x4; bf16 store; GEMM-A for xw) ----------
__global__ __launch_bounds__(256) void k_build_feats(
    const void* __restrict__ hc, const void* __restrict__ hd,
    const void* __restrict__ hs, uint16_t* __restrict__ feats,
    const int* __restrict__ flag) {
    int idx = blockIdx.x * 256 + threadIdx.x;   // 3072 blocks -> NBSD/4 threads
    int u = idx * 4;
    int isf = flag[0];
    float a[4], b[4], c[4];
    if (isf) {
        f32x4 va = *(const f32x4*)((const float*)hc + u);
        f32x4 vb = *(const f32x4*)((const float*)hd + u);
        f32x4 vc = *(const f32x4*)((const float*)hs + u);
        #pragma unroll
        for (int q = 0; q < 4; q++) { a[q] = va[q]; b[q] = vb[q]; c[q] = vc[q]; }
    } else {
        u16x4 va = *(const u16x4*)((const uint16_t*)hc + u);
        u16x4 vb = *(const u16x4*)((const uint16_t*)hd + u);
        u16x4 vc = *(const u16x4*)((const uint16_t*)hs + u);
        #pragma unroll
        for (int q = 0; q < 4; q++) { a[q] = b2f(va[q]); b[q] = b2f(vb[q]); c[q] = b2f(vc[q]); }
    }
    uint16_t o[12];
    #pragma unroll
    for (int q = 0; q < 4; q++) {
        o[3 * q] = f2b(a[q]); o[3 * q + 1] = f2b(b[q]); o[3 * q + 2] = f2b(c[q]);
    }
    u32x2 w0 = {pk2(o[0], o[1]), pk2(o[2], o[3])};
    u32x2 w1 = {pk2(o[4], o[5]), pk2(o[6], o[7])};
    u32x2 w2 = {pk2(o[8], o[9]), pk2(o[10], o[11])};
    *(u32x2*)(feats + (size_t)3 * u) = w0;
    *(u32x2*)(feats + (size_t)3 * u + 4) = w1;
    *(u32x2*)(feats + (size_t)3 * u + 8) = w2;
}

// ---------- F128 (first 128 nodes) hi/lo bf16 split ----------
__global__ __launch_bounds__(256) void k_build_f128(
    const void* __restrict__ hc, const void* __restrict__ hd,
    const void* __restrict__ hs, uint16_t* __restrict__ Fh,
    uint16_t* __restrict__ Fl, const int* __restrict__ flag) {
    int t = blockIdx.x * 256 + threadIdx.x;   // 384 blocks -> 98304
    int isf = flag[0];
    int n = t / DD, d = t - n * DD;
    float v = featAt(hc, hd, hs, n, d, isf);
    uint16_t h = f2b(v);
    Fh[t] = h;
    Fl[t] = f2b(v - b2f(h));
}

// ---------- G = F F^T via MFMA hi/lo (drops ll term, ~1e-5 rel err) ----------
__global__ __launch_bounds__(256)
void k_simgemm(const uint16_t* __restrict__ Fh, const uint16_t* __restrict__ Fl,
               float* __restrict__ G) {
    __shared__ __align__(16) uint16_t Ah[64 * 32], Al[64 * 32], Bh_[64 * 32], Bl_[64 * 32];
    const int tid = threadIdx.x, lane = tid & 63, wid = tid >> 6;
    const int wr = wid >> 1, wc = wid & 1;
    const int m0 = blockIdx.y * 64, n0 = blockIdx.x * 64;
    f32x4 acc[2][2];
    #pragma unroll
    for (int i = 0; i < 2; i++)
        #pragma unroll
        for (int j = 0; j < 2; j++) acc[i][j] = (f32x4){0.f, 0.f, 0.f, 0.f};
    const int sr = tid >> 2, sg = tid & 3;
    const int sgl = sg ^ ((sr >> 1) & 3);
    const int dofs = wid * 64 * 8;
    for (int k0 = 0; k0 < DD; k0 += 32) {
        gload16(Fh + (size_t)(m0 + sr) * DD + k0 + sgl * 8, Ah + dofs);
        gload16(Fl + (size_t)(m0 + sr) * DD + k0 + sgl * 8, Al + dofs);
        gload16(Fh + (size_t)(n0 + sr) * DD + k0 + sgl * 8, Bh_ + dofs);
        gload16(Fl + (size_t)(n0 + sr) * DD + k0 + sgl * 8, Bl_ + dofs);
        __syncthreads();
        bf16x8 ah[2], al[2], bh2[2], bl2[2];
        #pragma unroll
        for (int i = 0; i < 2; i++) {
            int r = wr * 32 + i * 16 + (lane & 15);
            int g = (lane >> 4) ^ ((r >> 1) & 3);
            ah[i] = *(const bf16x8*)(Ah + r * 32 + g * 8);
            al[i] = *(const bf16x8*)(Al + r * 32 + g * 8);
        }
        #pragma unroll
        for (int j = 0; j < 2; j++) {
            int r = wc * 32 + j * 16 + (lane & 15);
            int g = (lane >> 4) ^ ((r >> 1) & 3);
            bh2[j] = *(const bf16x8*)(Bh_ + r * 32 + g * 8);
            bl2[j] = *(const bf16x8*)(Bl_ + r * 32 + g * 8);
        }
        #pragma unroll
        for (int i = 0; i < 2; i++)
            #pragma unroll
            for (int j = 0; j < 2; j++)
                acc[i][j] = __builtin_amdgcn_mfma_f32_16x16x32_bf16(ah[i], bh2[j], acc[i][j], 0, 0, 0);
        #pragma unroll
        for (int i = 0; i < 2; i++)
            #pragma unroll
            for (int j = 0; j < 2; j++)
                acc[i][j] = __builtin_amdgcn_mfma_f32_16x16x32_bf16(ah[i], bl2[j], acc[i][j], 0, 0, 0);
        #pragma unroll
        for (int i = 0; i < 2; i++)
            #pragma unroll
            for (int j = 0; j < 2; j++)
                acc[i][j] = __builtin_amdgcn_mfma_f32_16x16x32_bf16(al[i], bh2[j], acc[i][j], 0, 0, 0);
        __syncthreads();
    }
    #pragma unroll
    for (int i = 0; i < 2; i++)
        #pragma unroll
        for (int j = 0; j < 2; j++) {
            int n = n0 + wc * 32 + j * 16 + (lane & 15);
            int mb = m0 + wr * 32 + i * 16 + ((lane >> 4) << 2);
            #pragma unroll
            for (int q = 0; q < 4; q++)
                G[(size_t)(mb + q) * SS + n] = acc[i][j][q];
        }
}

// ---------- nrm from G diag ----------
__global__ void k_simnorm(const float* __restrict__ G, float* __restrict__ nrm) {
    int i = threadIdx.x;   // <<<1,128>>>
    nrm[i] = fmaxf(sqrtf(G[(size_t)i * SS + i]), 1e-8f);
}

// ---------- normalize dots -> cos sims (in place) + minmax ----------
__global__ __launch_bounds__(256) void k_minmax2(float* __restrict__ simb,
                                                 const float* __restrict__ nrm,
                                                 float* __restrict__ mnmx) {
    int tid = threadIdx.x;
    float mn = 3.4e38f, mx = -3.4e38f;
    for (int e = tid; e < SS * SS; e += 256) {
        int i = e >> 7, j = e & 127;
        float v = simb[e] / (nrm[i] * nrm[j]);
        simb[e] = v;
        mn = fminf(mn, v); mx = fmaxf(mx, v);
    }
    __shared__ float rmn[256], rmx[256];
    rmn[tid] = mn; rmx[tid] = mx; __syncthreads();
    for (int o = 128; o > 0; o >>= 1) {
        if (tid < o) { rmn[tid] = fminf(rmn[tid], rmn[tid + o]); rmx[tid] = fmaxf(rmx[tid], rmx[tid + o]); }
        __syncthreads();
    }
    if (tid == 0) { mnmx[0] = rmn[0]; mnmx[1] = rmx[0]; }
}

// ---------- min-max normalize sims in place, deg/dinv ----------
__global__ __launch_bounds__(128) void k_deg(float* __restrict__ simb,
                                             const float* __restrict__ mnmx,
                                             float* __restrict__ deg,
                                             float* __restrict__ dinv) {
    int j = blockIdx.x, i = threadIdx.x;
    float mn = mnmx[0], inv = 1.f / (mnmx[1] - mnmx[0]);
    float s = (simb[i * SS + j] - mn) * inv;
    simb[i * SS + j] = s;
    __shared__ float red[128];
    red[i] = s; __syncthreads();
    for (int o = 64; o > 0; o >>= 1) { if (i < o) red[i] += red[i + o]; __syncthreads(); }
    if (i == 0) { float d = red[0] + 1.f; deg[j] = d; dinv[j] = rsqrtf(d); }
}

// ---------- GCN neighbor aggregate (j<128), grid (SS,3) ----------
__global__ __launch_bounds__(256) void k_agg(const float* __restrict__ simb,
                                             const float* __restrict__ dinv,
                                             const uint16_t* __restrict__ xw,
                                             float* __restrict__ aggb) {
    int j = blockIdx.x;
    int d = blockIdx.y * 256 + threadIdx.x;
    __shared__ float w[SS];
    if (threadIdx.x < SS) w[threadIdx.x] = dinv[threadIdx.x] * simb[threadIdx.x * SS + j] * dinv[j];
    __syncthreads();
    float s = 0.f;
    #pragma unroll 8
    for (int i = 0; i < SS; i++) s += w[i] * b2f(xw[(size_t)i * DD + d]);
    aggb[(size_t)j * DD + d] = s;
}

// ---------- GCN combine in place (vec x8, bf16 state) ----------
__global__ __launch_bounds__(256) void k_gcn_combine(uint16_t* __restrict__ xw,
                                                     const float* __restrict__ aggb,
                                                     const float* __restrict__ deg,
                                                     const void* __restrict__ gcnb,
                                                     const int* __restrict__ flag) {
    uint32_t t = (blockIdx.x * 256 + threadIdx.x) * 8u;   // 4608 blocks, exact
    int isf = flag[0];
    uint32_t n = t / 768u;
    uint32_t d0 = t - n * 768u;
    u16x8 xv = *(const u16x8*)(xw + t);
    float v[8];
    #pragma unroll
    for (int q = 0; q < 8; q++) v[q] = b2f(xv[q]);
    if (n < SS) {
        f32x4 a0 = *(const f32x4*)(aggb + t);
        f32x4 a1 = *(const f32x4*)(aggb + t + 4);
        float dg = deg[n];
        #pragma unroll
        for (int q = 0; q < 4; q++) { v[q] = v[q] / dg + a0[q]; v[q + 4] = v[q + 4] / dg + a1[q]; }
    }
    float bb[8];
    if (isf) {
        f32x4 b0 = *(const f32x4*)((const float*)gcnb + d0);
        f32x4 b1 = *(const f32x4*)((const float*)gcnb + d0 + 4);
        #pragma unroll
        for (int q = 0; q < 4; q++) { bb[q] = b0[q]; bb[q + 4] = b1[q]; }
    } else {
        u16x8 b8 = *(const u16x8*)((const uint16_t*)gcnb + d0);
        #pragma unroll
        for (int q = 0; q < 8; q++) bb[q] = b2f(b8[q]);
    }
    u16x8 ov;
    #pragma unroll
    for (int q = 0; q < 8; q++) ov[q] = f2b(fmaxf(v[q] + bb[q], 0.f));
    *(u16x8*)(xw + t) = ov;
}

// ---------- colsum over first 128 rows ----------
__global__ __launch_bounds__(256) void k_colsum(const uint16_t* __restrict__ x,
                                                float* __restrict__ svec) {
    int d = blockIdx.x * 256 + threadIdx.x;
    if (d < DD) {
        float s = 0.f;
        for (int i = 0; i < SS; i++) s += b2f(x[(size_t)i * DD + d]);
        svec[d] = s;
    }
}

// ---------- mvec = svec @ ggc_W[l] ----------
__global__ __launch_bounds__(256) void k_matvec(const float* __restrict__ svec,
                                                const void* __restrict__ Wg, size_t ofs,
                                                float* __restrict__ mvec,
                                                const int* __restrict__ flag) {
    int k = blockIdx.x * 256 + threadIdx.x;
    int isf = flag[0];
    if (k < DD) {
        float s = 0.f;
        for (int d = 0; d < DD; d++) s += svec[d] * loadf(Wg, ofs + (size_t)d * DD + k, isf);
        mvec[k] = s;
    }
}

// ---------- giE = mvec @ wih.T + bih ----------
__global__ __launch_bounds__(256) void k_rowdot(const float* __restrict__ mvec,
                                                const void* __restrict__ wih,
                                                const void* __restrict__ bih,
                                                float* __restrict__ giE,
                                                const int* __restrict__ flag) {
    int rr = blockIdx.x, tid = threadIdx.x;
    int isf = flag[0];
    float s = 0.f;
    for (int k = tid; k < DD; k += 256) s += mvec[k] * loadf(wih, (size_t)rr * DD + k, isf);
    __shared__ float red[256];
    red[tid] = s; __syncthreads();
    for (int o = 128; o > 0; o >>= 1) { if (tid < o) red[tid] += red[tid + o]; __syncthreads(); }
    if (tid == 0) giE[rr] = red[0] + loadf(bih, rr, isf);
}

// ---------- y = h_feature + relu(x_g), batched all 3 chunks, vec x8 ----------
__global__ __launch_bounds__(256) void k_build_y(const void* __restrict__ hf,
                                                 const uint16_t* __restrict__ xg,
                                                 uint16_t* __restrict__ y,
                                                 const int* __restrict__ flag) {
    uint32_t t = (blockIdx.x * 256 + threadIdx.x) * 8u;   // 4608 blocks, exact TOTAL_ND
    int isf = flag[0];
    uint32_t u = t;
    if (u >= 2u * NBSD) u -= 2u * NBSD; else if (u >= NBSD) u -= NBSD;
    u16x8 xv = *(const u16x8*)(xg + t);
    float h[8];
    if (isf) {
        f32x4 h0 = *(const f32x4*)((const float*)hf + u);
        f32x4 h1 = *(const f32x4*)((const float*)hf + u + 4);
        #pragma unroll
        for (int q = 0; q < 4; q++) { h[q] = h0[q]; h[q + 4] = h1[q]; }
    } else {
        u16x8 h8 = *(const u16x8*)((const uint16_t*)hf + u);
        #pragma unroll
        for (int q = 0; q < 8; q++) h[q] = b2f(h8[q]);
    }
    u16x8 ov;
    #pragma unroll
    for (int q = 0; q < 8; q++) ov[q] = f2b(h[q] + fmaxf(b2f(xv[q]), 0.f));
    *(u16x8*)(y + t) = ov;
}

// ---------- LayerNorm (batched: 12288 rows, per-g weight select) ----------
__global__ __launch_bounds__(256) void k_ln(const uint16_t* __restrict__ tin,
                                            const void* g0, const void* b0,
                                            const void* g1, const void* b1,
                                            const void* g2, const void* b2,
                                            float* __restrict__ out,
                                            const int* __restrict__ flag) {
    int m = blockIdx.x, tid = threadIdx.x;
    int isf = flag[0];
    int gs = m >> 12;
    const void* gw = (gs == 0) ? g0 : (gs == 1) ? g1 : g2;
    const void* bw = (gs == 0) ? b0 : (gs == 1) ? b1 : b2;
    float v0 = b2f(tin[(size_t)m * DD + tid]);
    float v1 = b2f(tin[(size_t)m * DD + tid + 256]);
    float v2 = b2f(tin[(size_t)m * DD + tid + 512]);
    __shared__ float red[256];
    red[tid] = v0 + v1 + v2; __syncthreads();
    for (int o = 128; o > 0; o >>= 1) { if (tid < o) red[tid] += red[tid + o]; __syncthreads(); }
    float mu = red[0] * (1.f / 768.f);
    __syncthreads();
    float d0 = v0 - mu, d1 = v1 - mu, d2 = v2 - mu;
    red[tid] = d0 * d0 + d1 * d1 + d2 * d2; __syncthreads();
    for (int o = 128; o > 0; o >>= 1) { if (tid < o) red[tid] += red[tid + o]; __syncthreads(); }
    float rstd = rsqrtf(red[0] * (1.f / 768.f) + 1e-5f);
    out[(size_t)m * DD + tid]       = d0 * rstd * loadf(gw, tid, isf)       + loadf(bw, tid, isf);
    out[(size_t)m * DD + tid + 256] = d1 * rstd * loadf(gw, tid + 256, isf) + loadf(bw, tid + 256, isf);
    out[(size_t)m * DD + tid + 512] = d2 * rstd * loadf(gw, tid + 512, isf) + loadf(bw, tid + 512, isf);
}

// ---------- weight convert: hi/lo bf16 split, elementwise vec x4 ----------
__global__ __launch_bounds__(256) void k_cvt2(const void* __restrict__ src,
                                              uint16_t* __restrict__ dh,
                                              uint16_t* __restrict__ dl, int n,
                                              const int* __restrict__ flag) {
    int t = (blockIdx.x * 256 + threadIdx.x) * 4;   // exact cover
    int isf = flag[0];
    float v[4];
    if (isf) {
        f32x4 s = *(const f32x4*)((const float*)src + t);
        #pragma unroll
        for (int q = 0; q < 4; q++) v[q] = s[q];
    } else {
        u16x4 s = *(const u16x4*)((const uint16_t*)src + t);
        #pragma unroll
        for (int q = 0; q < 4; q++) v[q] = b2f(s[q]);
    }
    u16x4 hh, ll;
    #pragma unroll
    for (int q = 0; q < 4; q++) {
        uint16_t h = f2b(v[q]);
        hh[q] = h;
        ll[q] = f2b(v[q] - b2f(h));
    }
    *(u16x4*)(dh + t) = hh;
    *(u16x4*)(dl + t) = ll;
}

// ---------- weight convert: transpose + hi/lo split, 7 matrices batched ----------
// z=0: gcn_W -> gdst; z=1..6: head weights -> tail slots (W1g0,W2g0,W1g1,W2g1,W1g2,W2g2)
__global__ __launch_bounds__(256) void k_cvtT7(const void* s0, const void* s1,
                                               const void* s2, const void* s3,
                                               const void* s4, const void* s5,
                                               const void* s6,
                                               uint16_t* __restrict__ gdst,
                                               uint16_t* __restrict__ tail,
                                               const int* __restrict__ flag) {
    __shared__ float tile[64][65];
    int isf = flag[0];
    int z = blockIdx.z;
    const void* src = (z == 0) ? s0 : (z == 1) ? s1 : (z == 2) ? s2 :
                      (z == 3) ? s3 : (z == 4) ? s4 : (z == 5) ? s5 : s6;
    uint16_t* dh = (z == 0) ? gdst : tail + (size_t)(z - 1) * WSLOT;
    uint16_t* dl = dh + WMAT;
    int k0 = blockIdx.x * 64, n0 = blockIdx.y * 64;
    for (int t = threadIdx.x; t < 4096; t += 256) {
        int r = t >> 6, c = t & 63;
        tile[r][c] = loadf(src, (size_t)(k0 + r) * DD + n0 + c, isf);
    }
    __syncthreads();
    for (int t = threadIdx.x; t < 4096; t += 256) {
        int r = t >> 6, c = t & 63;
        float v = tile[c][r];
        uint16_t h = f2b(v);
        size_t o = (size_t)(n0 + r) * DD + k0 + c;
        dh[o] = h;
        dl[o] = f2b(v - b2f(h));
    }
}

// =============== MFMA GEMM: C[M,768] = A[M,768] @ BT^T, bf16 hi/lo combined ====
// BT layout: [768][768] row = output col n, col = k; lo residual at BT+WMAT.
// 128x128 tile, BK=32, 4 waves; both halves in ONE K-loop (A staged once).
// z-batched (aZ/bZ/cZ strides); XCD-bijective block swizzle.
enum { EPI_NONE = 0, EPI_BIAS_RELU = 3, EPI_BIAS = 4 };

template<int EPI>
__global__ __launch_bounds__(256)
void k_mgemm(const uint16_t* __restrict__ A, uint32_t aZ,
             const uint16_t* __restrict__ BTh, uint32_t bZ,
             const void* bias0, const void* bias1, const void* bias2,
             uint16_t* __restrict__ C, uint32_t cZ,
             const int* __restrict__ flag) {
    __shared__ __align__(16) uint16_t As[128 * 32];
    __shared__ __align__(16) uint16_t Bs[2][128 * 32];
    const int isf = flag[0];
    const int tid = threadIdx.x, lane = tid & 63, wid = tid >> 6;
    const int wr = wid >> 1, wc = wid & 1;
    int bx = blockIdx.x, by = blockIdx.y;
    xcd_swz(bx, by, gridDim.x, gridDim.y);
    const int z = blockIdx.z;
    const uint16_t* Az = A + (size_t)z * aZ;
    const uint16_t* Bh = BTh + (size_t)z * bZ;
    const uint16_t* Bl = Bh + WMAT;
    uint16_t* Cz = C + (size_t)z * cZ;
    const void* bias = (z == 0) ? bias0 : (z == 1) ? bias1 : bias2;
    const int m0 = by * 128, n0 = bx * 128;

    f32x4 acc[4][4];
    #pragma unroll
    for (int i = 0; i < 4; i++)
        #pragma unroll
        for (int j = 0; j < 4; j++) acc[i][j] = (f32x4){0.f, 0.f, 0.f, 0.f};

    for (int k0 = 0; k0 < DD; k0 += 32) {
        #pragma unroll
        for (int rd = 0; rd < 2; rd++) {
            int c = rd * 256 + tid;
            int r = c >> 2, g = c & 3;
            int gl = g ^ ((r >> 1) & 3);               // pre-swizzled source
            int dofs = (rd * 256 + wid * 64) * 8;
            gload16(Az + (size_t)(m0 + r) * DD + k0 + gl * 8, As + dofs);
            gload16(Bh + (size_t)(n0 + r) * DD + k0 + gl * 8, Bs[0] + dofs);
            if (isf) gload16(Bl + (size_t)(n0 + r) * DD + k0 + gl * 8, Bs[1] + dofs);
        }
        __syncthreads();
        bf16x8 af[4], bh4[4], bl4[4];
        #pragma unroll
        for (int i = 0; i < 4; i++) {
            int r = wr * 64 + i * 16 + (lane & 15);
            int g = (lane >> 4) ^ ((r >> 1) & 3);
            af[i] = *(const bf16x8*)(As + r * 32 + g * 8);
        }
        #pragma unroll
        for (int j = 0; j < 4; j++) {
            int r = wc * 64 + j * 16 + (lane & 15);
            int g = (lane >> 4) ^ ((r >> 1) & 3);
            bh4[j] = *(const bf16x8*)(Bs[0] + r * 32 + g * 8);
            if (isf) bl4[j] = *(const bf16x8*)(Bs[1] + r * 32 + g * 8);
        }
        #pragma unroll
        for (int i = 0; i < 4; i++)
            #pragma unroll
            for (int j = 0; j < 4; j++)
                acc[i][j] = __builtin_amdgcn_mfma_f32_16x16x32_bf16(af[i], bh4[j], acc[i][j], 0, 0, 0);
        if (isf) {
            #pragma unroll
            for (int i = 0; i < 4; i++)
                #pragma unroll
                for (int j = 0; j < 4; j++)
                    acc[i][j] = __builtin_amdgcn_mfma_f32_16x16x32_bf16(af[i], bl4[j], acc[i][j], 0, 0, 0);
        }
        __syncthreads();
    }
    // D layout: col = lane&15, row = (lane>>4)*4 + q
    #pragma unroll
    for (int i = 0; i < 4; i++) {
        #pragma unroll
        for (int j = 0; j < 4; j++) {
            int n = n0 + wc * 64 + j * 16 + (lane & 15);
            int mb = m0 + wr * 64 + i * 16 + ((lane >> 4) << 2);
            float bv = 0.f;
            if (EPI != EPI_NONE) bv = loadf(bias, n, isf);
            #pragma unroll
            for (int q = 0; q < 4; q++) {
                float v = acc[i][j][q];
                if (EPI == EPI_BIAS_RELU) v = fmaxf(v + bv, 0.f);
                else if (EPI == EPI_BIAS) v = v + bv;
                Cz[(size_t)(mb + q) * DD + n] = f2b(v);
            }
        }
    }
}

// =============== MFMA fused GRU layer: 3-gate GEMM (hi/lo combined) + cell ====
// 64x64 block (per gate), 4 waves of 32x32, grid (12,192), XCD swizzle.
__global__ __launch_bounds__(256)
void k_grum(const uint16_t* __restrict__ X,
            const uint16_t* __restrict__ Wh, const uint16_t* __restrict__ Wl,
            const void* __restrict__ bih, const void* __restrict__ bhh,
            const float* __restrict__ giE, uint16_t* __restrict__ Xn,
            const int* __restrict__ flag) {
    __shared__ __align__(16) uint16_t As[64 * 32];
    __shared__ __align__(16) uint16_t Bs[3][2][64 * 32];
    const int isf = flag[0];
    const int tid = threadIdx.x, lane = tid & 63, wid = tid >> 6;
    const int wr = wid >> 1, wc = wid & 1;
    int bx = blockIdx.x, by = blockIdx.y;
    xcd_swz(bx, by, gridDim.x, gridDim.y);
    const int n0 = bx * 64, m0 = by * 64;

    f32x4 acc[3][2][2];
    #pragma unroll
    for (int gg = 0; gg < 3; gg++)
        #pragma unroll
        for (int i = 0; i < 2; i++)
            #pragma unroll
            for (int j = 0; j < 2; j++) acc[gg][i][j] = (f32x4){0.f, 0.f, 0.f, 0.f};

    const int sr = tid >> 2, sg = tid & 3;
    const int sgl = sg ^ ((sr >> 1) & 3);
    const int dofs = wid * 64 * 8;

    for (int k0 = 0; k0 < DD; k0 += 32) {
        gload16(X + (size_t)(m0 + sr) * DD + k0 + sgl * 8, As + dofs);
        #pragma unroll
        for (int gg = 0; gg < 3; gg++) {
            size_t bro = (size_t)(gg * DD + n0 + sr) * DD + k0 + sgl * 8;
            gload16(Wh + bro, Bs[gg][0] + dofs);
            if (isf) gload16(Wl + bro, Bs[gg][1] + dofs);
        }
        __syncthreads();
        bf16x8 af[2];
        #pragma unroll
        for (int i = 0; i < 2; i++) {
            int r = wr * 32 + i * 16 + (lane & 15);
            int g = (lane >> 4) ^ ((r >> 1) & 3);
            af[i] = *(const bf16x8*)(As + r * 32 + g * 8);
        }
        #pragma unroll
        for (int gg = 0; gg < 3; gg++) {
            bf16x8 bh2[2], bl2[2];
            #pragma unroll
            for (int j = 0; j < 2; j++) {
                int r = wc * 32 + j * 16 + (lane & 15);
                int g = (lane >> 4) ^ ((r >> 1) & 3);
                bh2[j] = *(const bf16x8*)(Bs[gg][0] + r * 32 + g * 8);
                if (isf) bl2[j] = *(const bf16x8*)(Bs[gg][1] + r * 32 + g * 8);
            }
            #pragma unroll
            for (int j = 0; j < 2; j++)
                #pragma unroll
                for (int i = 0; i < 2; i++)
                    acc[gg][i][j] = __builtin_amdgcn_mfma_f32_16x16x32_bf16(af[i], bh2[j], acc[gg][i][j], 0, 0, 0);
            if (isf) {
                #pragma unroll
                for (int j = 0; j < 2; j++)
                    #pragma unroll
                    for (int i = 0; i < 2; i++)
                        acc[gg][i][j] = __builtin_amdgcn_mfma_f32_16x16x32_bf16(af[i], bl2[j], acc[gg][i][j], 0, 0, 0);
            }
        }
        __syncthreads();
    }
    // epilogue: full GRU cell pointwise
    #pragma unroll
    for (int i = 0; i < 2; i++) {
        #pragma unroll
        for (int j = 0; j < 2; j++) {
            int n = n0 + wc * 32 + j * 16 + (lane & 15);
            int mb = m0 + wr * 32 + i * 16 + ((lane >> 4) << 2);
            float bh0 = loadf(bhh, n, isf);
            float bh1 = loadf(bhh, DD + n, isf);
            float bh2v = loadf(bhh, 2 * DD + n, isf);
            float gE0 = giE[n], gE1 = giE[DD + n], gE2 = giE[2 * DD + n];
            float bi0 = loadf(bih, n, isf);
            float bi1 = loadf(bih, DD + n, isf);
            float bi2 = loadf(bih, 2 * DD + n, isf);
            #pragma unroll
            for (int q = 0; q < 4; q++) {
                int m = mb + q;
                bool msg = (m < SS);
                float gr = msg ? gE0 : bi0;
                float gz = msg ? gE1 : bi1;
                float gn = msg ? gE2 : bi2;
                float rg = 1.f / (1.f + expf(-(acc[0][i][j][q] + bh0 + gr)));
                float zg = 1.f / (1.f + expf(-(acc[1][i][j][q] + bh1 + gz)));
                float hn = acc[2][i][j][q] + bh2v;
                float nn = tanhf(gn + rg * hn);
                float xo = b2f(X[(size_t)m * DD + n]);
                Xn[(size_t)m * DD + n] = f2b((1.f - zg) * nn + zg * xo);
            }
        }
    }
}

// ============================== driver ==============================
extern "C" void kernel_launch(void* const* d_in, const int* in_sizes, int n_in,
                              void* d_out, int out_size, void* d_ws, size_t ws_size,
                              hipStream_t stream) {
    float* OUTF = (float*)d_out;            // FINAL output: fp32
    uint16_t* OB = (uint16_t*)d_out;        // first 18.9MB of d_out as bf16 trunk/H scratch

    static const int expect[29] = {
        3145728,3145728,3145728,3145728, 589824,768, 1179648, 1769472,1769472, 2304,2304,
        589824,768,589824,768,768,768,
        589824,768,589824,768,768,768,
        589824,768,589824,768,768,768 };
    int bad = -1;
    if (n_in != 29) bad = 90;
    else { for (int i = 0; i < 29; i++) if (in_sizes[i] != expect[i]) { bad = i; break; } }
    if (bad < 0 && out_size != (int)TOTAL_ND) bad = 91;
    if (bad < 0 && ws_size < 33ull * 1024 * 1024) bad = 92;
    if (bad >= 0) {
        k_diag<<<1, 64, 0, stream>>>(OUTF, 10000.f + 100.f * (float)bad);
        return;
    }

    // ws layout (floats): small scratch | F128 hi/lo | W0 | WH | WT  (~30.8 MiB)
    float* fbase = (float*)d_ws;
    float* simb = fbase;                        // 16384
    float* nrm  = simb + 16384;                 // 128
    float* mnmx = nrm + 128;                    // 2
    float* deg  = mnmx + 2;                     // 128
    float* dinv = deg + 128;                    // 128
    float* aggb = dinv + 128;                   // 98304
    float* svec = aggb + 98304;                 // 768
    float* mvec = svec + 768;                   // 768
    float* giE  = mvec + 768;                   // 2304
    int*   flag = (int*)(giE + 2304);           // at 118914
    uint16_t* F128h = (uint16_t*)(fbase + 118916);  // 98304 u16
    uint16_t* F128l = (uint16_t*)(fbase + 168068);  // 98304 u16
    uint16_t* W0 = (uint16_t*)(fbase + 217220);     // 9,437,184 u16
    uint16_t* WH = W0 + TOTAL_ND;                   // 3,145,728 u16 slots
    uint16_t* WT = WH + NBSD;                       // 3,145,728 u16 slots

    // head weights hi/lo live in the TAIL of d_out (last 13.5 MB; dead before LN)
    uint16_t* tailW = (uint16_t*)((char*)d_out + 23592960);  // 6 slots x WSLOT

    const void* hf = d_in[0];
    const void* hc = d_in[1];
    const void* hd = d_in[2];
    const void* hs = d_in[3];

    k_probe<<<1, 64, 0, stream>>>(hf, flag);

    // ---- all transpose-weight conversions batched (gcn_W -> WH, heads -> tail) ----
    k_cvtT7<<<dim3(12, 12, 7), 256, 0, stream>>>(
        d_in[4], d_in[11], d_in[13], d_in[17], d_in[19], d_in[23], d_in[25],
        WH, tailW, flag);

    // ---- GCN front-end ----
    k_build_feats<<<3072, 256, 0, stream>>>(hc, hd, hs, W0, flag);
    k_build_f128<<<384, 256, 0, stream>>>(hc, hd, hs, F128h, F128l, flag);
    k_simgemm<<<dim3(2, 2), 256, 0, stream>>>(F128h, F128l, simb);
    k_simnorm<<<1, 128, 0, stream>>>(simb, nrm);
    k_minmax2<<<1, 256, 0, stream>>>(simb, nrm, mnmx);
    k_deg<<<SS, SS, 0, stream>>>(simb, mnmx, deg, dinv);
    k_mgemm<EPI_NONE><<<dim3(6, 96, 1), 256, 0, stream>>>(
        W0, 0, WH, 0, nullptr, nullptr, nullptr, OB, 0, flag);
    k_agg<<<dim3(SS, 3), 256, 0, stream>>>(simb, dinv, OB, aggb);
    k_gcn_combine<<<4608, 256, 0, stream>>>(OB, aggb, deg, d_in[5], flag);

    // ---- GatedGraphConv: whh hi->WH, lo->WT (gcn_W in WH now dead) ----
    k_cvt2<<<1728, 256, 0, stream>>>(d_in[8], WH, WT, 1769472, flag);

    k_colsum<<<3, 256, 0, stream>>>(OB, svec);
    k_matvec<<<3, 256, 0, stream>>>(svec, d_in[6], 0, mvec, flag);
    k_rowdot<<<2304, 256, 0, stream>>>(mvec, d_in[7], d_in[9], giE, flag);
    k_grum<<<dim3(12, 192), 256, 0, stream>>>(OB, WH, WT, d_in[9], d_in[10], giE, W0, flag);

    k_colsum<<<3, 256, 0, stream>>>(W0, svec);
    k_matvec<<<3, 256, 0, stream>>>(svec, d_in[6], (size_t)DD * DD, mvec, flag);
    k_rowdot<<<2304, 256, 0, stream>>>(mvec, d_in[7], d_in[9], giE, flag);
    k_grum<<<dim3(12, 192), 256, 0, stream>>>(W0, WH, WT, d_in[9], d_in[10], giE, OB, flag);

    // ---- y = hf + relu(x) for all 3 chunks (OB -> W0); OB then dead ----
    k_build_y<<<4608, 256, 0, stream>>>(hf, OB, W0, flag);

    // ---- heads batched over z: y(W0) -> H(OB) -> T(W0) -> LN(d_out) ----
    k_mgemm<EPI_BIAS_RELU><<<dim3(6, 32, 3), 256, 0, stream>>>(
        W0, NBSD, tailW, 2 * WSLOT, d_in[12], d_in[18], d_in[24], OB, NBSD, flag);
    k_mgemm<EPI_BIAS><<<dim3(6, 32, 3), 256, 0, stream>>>(
        OB, NBSD, tailW + WSLOT, 2 * WSLOT, d_in[14], d_in[20], d_in[26], W0, NBSD, flag);
    k_ln<<<NNODE, 256, 0, stream>>>(W0, d_in[15], d_in[16], d_in[21], d_in[22],
                                    d_in[27], d_in[28], OUTF, flag);
}

// Round 3
// 942.832 us; speedup vs baseline: 4.6633x; 1.0391x over previous
//
#include <hip/hip_runtime.h>
#include <cstdint>
#include <cstddef>

#define DD 768
#define SS 128
#define NNODE 12288            // 3*B*S
#define NBS 4096               // B*S
#define NBSD 3145728           // B*S*D (per-chunk elements)
#define TOTAL_ND 9437184ULL    // NNODE*DD == out_size (fp32 elements)
#define WMAT 589824            // 768*768
#define WSLOT 1179648          // hi+lo pair of one 768x768 matrix (u16 elems)

typedef __attribute__((ext_vector_type(4))) float f32x4;
typedef __attribute__((ext_vector_type(8))) short bf16x8;
typedef __attribute__((ext_vector_type(4))) uint16_t u16x4;
typedef __attribute__((ext_vector_type(2))) uint16_t u16x2;
typedef __attribute__((ext_vector_type(8))) uint16_t u16x8;
typedef __attribute__((ext_vector_type(2))) uint32_t u32x2;

__device__ __forceinline__ float b2f(uint16_t u) {
    union { uint32_t i; float f; } x; x.i = ((uint32_t)u) << 16; return x.f;
}
__device__ __forceinline__ uint16_t f2b(float f) {
    uint32_t x = __float_as_uint(f);
    return (uint16_t)((x + 0x7FFFu + ((x >> 16) & 1u)) >> 16);
}
__device__ __forceinline__ float loadf(const void* p, size_t i, int isf32) {
    return isf32 ? ((const float*)p)[i] : b2f(((const uint16_t*)p)[i]);
}
// feats[n][d] = src_{d%3}[n*256 + d/3]
__device__ __forceinline__ float featAt(const void* hc, const void* hd, const void* hs,
                                        int n, int d, int isf) {
    int w = d % 3;
    size_t u = (size_t)n * 256 + (size_t)(d / 3);
    const void* p = (w == 0) ? hc : (w == 1) ? hd : hs;
    return loadf(p, u, isf);
}
__device__ __forceinline__ uint32_t pk2(uint16_t a, uint16_t b) {
    return (uint32_t)a | ((uint32_t)b << 16);
}

// async 16B global->LDS (linear dest: wave-uniform base + lane*16)
__device__ __forceinline__ void gload16(const uint16_t* g, uint16_t* l) {
    __builtin_amdgcn_global_load_lds(
        (__attribute__((address_space(1))) uint32_t*)(uintptr_t)g,
        (__attribute__((address_space(3))) uint32_t*)l, 16, 0, 0);
}

// ---------- diag beacon ----------
__global__ void k_diag(float* out, float code) {
    if (threadIdx.x == 0 && blockIdx.x == 0) out[0] = code;
}

// ---------- dtype probe ----------
__global__ void k_probe(const void* hf, int* flag) {
    if (threadIdx.x == 0 && blockIdx.x == 0) {
        const uint32_t* w = (const uint32_t*)hf;
        int bad = 0;
        for (int k = 0; k < 64; k++) {
            uint16_t lo = (uint16_t)(w[k] & 0xFFFFu);
            int e = (lo >> 7) & 0xFF;
            if (e < 100 || e > 140) bad++;
        }
        flag[0] = (bad > 24) ? 1 : 0;
    }
}

// ---------- feats build (vec x4; bf16 store; GEMM-A for xw) ----------
__global__ __launch_bounds__(256) void k_build_feats(
    const void* __restrict__ hc, const void* __restrict__ hd,
    const void* __restrict__ hs, uint16_t* __restrict__ feats,
    const int* __restrict__ flag) {
    int idx = blockIdx.x * 256 + threadIdx.x;   // 3072 blocks -> NBSD/4 threads
    int u = idx * 4;
    int isf = flag[0];
    float a[4], b[4], c[4];
    if (isf) {
        f32x4 va = *(const f32x4*)((const float*)hc + u);
        f32x4 vb = *(const f32x4*)((const float*)hd + u);
        f32x4 vc = *(const f32x4*)((const float*)hs + u);
        #pragma unroll
        for (int q = 0; q < 4; q++) { a[q] = va[q]; b[q] = vb[q]; c[q] = vc[q]; }
    } else {
        u16x4 va = *(const u16x4*)((const uint16_t*)hc + u);
        u16x4 vb = *(const u16x4*)((const uint16_t*)hd + u);
        u16x4 vc = *(const u16x4*)((const uint16_t*)hs + u);
        #pragma unroll
        for (int q = 0; q < 4; q++) { a[q] = b2f(va[q]); b[q] = b2f(vb[q]); c[q] = b2f(vc[q]); }
    }
    uint16_t o[12];
    #pragma unroll
    for (int q = 0; q < 4; q++) {
        o[3 * q] = f2b(a[q]); o[3 * q + 1] = f2b(b[q]); o[3 * q + 2] = f2b(c[q]);
    }
    u32x2 w0 = {pk2(o[0], o[1]), pk2(o[2], o[3])};
    u32x2 w1 = {pk2(o[4], o[5]), pk2(o[6], o[7])};
    u32x2 w2 = {pk2(o[8], o[9]), pk2(o[10], o[11])};
    *(u32x2*)(feats + (size_t)3 * u) = w0;
    *(u32x2*)(feats + (size_t)3 * u + 4) = w1;
    *(u32x2*)(feats + (size_t)3 * u + 8) = w2;
}

// ---------- F128 (first 128 nodes) hi/lo bf16 split ----------
__global__ __launch_bounds__(256) void k_build_f128(
    const void* __restrict__ hc, const void* __restrict__ hd,
    const void* __restrict__ hs, uint16_t* __restrict__ Fh,
    uint16_t* __restrict__ Fl, const int* __restrict__ flag) {
    int t = blockIdx.x * 256 + threadIdx.x;   // 384 blocks -> 98304
    int isf = flag[0];
    int n = t / DD, d = t - n * DD;
    float v = featAt(hc, hd, hs, n, d, isf);
    uint16_t h = f2b(v);
    Fh[t] = h;
    Fl[t] = f2b(v - b2f(h));
}

// ---------- G = F F^T via MFMA hi/lo (drops ll term, ~1e-5 rel err) ----------
__global__ __launch_bounds__(256)
void k_simgemm(const uint16_t* __restrict__ Fh, const uint16_t* __restrict__ Fl,
               float* __restrict__ G) {
    __shared__ __align__(16) uint16_t Ah[64 * 32], Al[64 * 32], Bh_[64 * 32], Bl_[64 * 32];
    const int tid = threadIdx.x, lane = tid & 63, wid = tid >> 6;
    const int wr = wid >> 1, wc = wid & 1;
    const int m0 = blockIdx.y * 64, n0 = blockIdx.x * 64;
    f32x4 acc[2][2];
    #pragma unroll
    for (int i = 0; i < 2; i++)
        #pragma unroll
        for (int j = 0; j < 2; j++) acc[i][j] = (f32x4){0.f, 0.f, 0.f, 0.f};
    const int sr = tid >> 2, sg = tid & 3;
    const int sgl = sg ^ ((sr >> 1) & 3);
    const int dofs = wid * 64 * 8;
    for (int k0 = 0; k0 < DD; k0 += 32) {
        gload16(Fh + (size_t)(m0 + sr) * DD + k0 + sgl * 8, Ah + dofs);
        gload16(Fl + (size_t)(m0 + sr) * DD + k0 + sgl * 8, Al + dofs);
        gload16(Fh + (size_t)(n0 + sr) * DD + k0 + sgl * 8, Bh_ + dofs);
        gload16(Fl + (size_t)(n0 + sr) * DD + k0 + sgl * 8, Bl_ + dofs);
        __syncthreads();
        bf16x8 ah[2], al[2], bh2[2], bl2[2];
        #pragma unroll
        for (int i = 0; i < 2; i++) {
            int r = wr * 32 + i * 16 + (lane & 15);
            int g = (lane >> 4) ^ ((r >> 1) & 3);
            ah[i] = *(const bf16x8*)(Ah + r * 32 + g * 8);
            al[i] = *(const bf16x8*)(Al + r * 32 + g * 8);
        }
        #pragma unroll
        for (int j = 0; j < 2; j++) {
            int r = wc * 32 + j * 16 + (lane & 15);
            int g = (lane >> 4) ^ ((r >> 1) & 3);
            bh2[j] = *(const bf16x8*)(Bh_ + r * 32 + g * 8);
            bl2[j] = *(const bf16x8*)(Bl_ + r * 32 + g * 8);
        }
        #pragma unroll
        for (int i = 0; i < 2; i++)
            #pragma unroll
            for (int j = 0; j < 2; j++)
                acc[i][j] = __builtin_amdgcn_mfma_f32_16x16x32_bf16(ah[i], bh2[j], acc[i][j], 0, 0, 0);
        #pragma unroll
        for (int i = 0; i < 2; i++)
            #pragma unroll
            for (int j = 0; j < 2; j++)
                acc[i][j] = __builtin_amdgcn_mfma_f32_16x16x32_bf16(ah[i], bl2[j], acc[i][j], 0, 0, 0);
        #pragma unroll
        for (int i = 0; i < 2; i++)
            #pragma unroll
            for (int j = 0; j < 2; j++)
                acc[i][j] = __builtin_amdgcn_mfma_f32_16x16x32_bf16(al[i], bh2[j], acc[i][j], 0, 0, 0);
        __syncthreads();
    }
    #pragma unroll
    for (int i = 0; i < 2; i++)
        #pragma unroll
        for (int j = 0; j < 2; j++) {
            int n = n0 + wc * 32 + j * 16 + (lane & 15);
            int mb = m0 + wr * 32 + i * 16 + ((lane >> 4) << 2);
            #pragma unroll
            for (int q = 0; q < 4; q++)
                G[(size_t)(mb + q) * SS + n] = acc[i][j][q];
        }
}

// ---------- sim post: nrm from diag -> cos normalize (in place) -> minmax ----------
__global__ __launch_bounds__(256) void k_simpost(float* __restrict__ simb,
                                                 float* __restrict__ mnmx) {
    int tid = threadIdx.x;
    __shared__ float nrmS[SS];
    if (tid < SS) nrmS[tid] = fmaxf(sqrtf(simb[(size_t)tid * SS + tid]), 1e-8f);
    __syncthreads();
    float mn = 3.4e38f, mx = -3.4e38f;
    for (int e = tid; e < SS * SS; e += 256) {
        int i = e >> 7, j = e & 127;
        float v = simb[e] / (nrmS[i] * nrmS[j]);
        simb[e] = v;
        mn = fminf(mn, v); mx = fmaxf(mx, v);
    }
    __shared__ float rmn[256], rmx[256];
    rmn[tid] = mn; rmx[tid] = mx; __syncthreads();
    for (int o = 128; o > 0; o >>= 1) {
        if (tid < o) { rmn[tid] = fminf(rmn[tid], rmn[tid + o]); rmx[tid] = fmaxf(rmx[tid], rmx[tid + o]); }
        __syncthreads();
    }
    if (tid == 0) { mnmx[0] = rmn[0]; mnmx[1] = rmx[0]; }
}

// ---------- min-max normalize sims in place, deg/dinv ----------
__global__ __launch_bounds__(128) void k_deg(float* __restrict__ simb,
                                             const float* __restrict__ mnmx,
                                             float* __restrict__ deg,
                                             float* __restrict__ dinv) {
    int j = blockIdx.x, i = threadIdx.x;
    float mn = mnmx[0], inv = 1.f / (mnmx[1] - mnmx[0]);
    float s = (simb[i * SS + j] - mn) * inv;
    simb[i * SS + j] = s;
    __shared__ float red[128];
    red[i] = s; __syncthreads();
    for (int o = 64; o > 0; o >>= 1) { if (i < o) red[i] += red[i + o]; __syncthreads(); }
    if (i == 0) { float d = red[0] + 1.f; deg[j] = d; dinv[j] = rsqrtf(d); }
}

// ---------- GCN neighbor aggregate (j<128), grid (SS,3) ----------
__global__ __launch_bounds__(256) void k_agg(const float* __restrict__ simb,
                                             const float* __restrict__ dinv,
                                             const uint16_t* __restrict__ xw,
                                             float* __restrict__ aggb) {
    int j = blockIdx.x;
    int d = blockIdx.y * 256 + threadIdx.x;
    __shared__ float w[SS];
    if (threadIdx.x < SS) w[threadIdx.x] = dinv[threadIdx.x] * simb[threadIdx.x * SS + j] * dinv[j];
    __syncthreads();
    float s = 0.f;
    #pragma unroll 8
    for (int i = 0; i < SS; i++) s += w[i] * b2f(xw[(size_t)i * DD + d]);
    aggb[(size_t)j * DD + d] = s;
}

// ---------- GCN combine in place (vec x8, bf16 state) ----------
__global__ __launch_bounds__(256) void k_gcn_combine(uint16_t* __restrict__ xw,
                                                     const float* __restrict__ aggb,
                                                     const float* __restrict__ deg,
                                                     const void* __restrict__ gcnb,
                                                     const int* __restrict__ flag) {
    uint32_t t = (blockIdx.x * 256 + threadIdx.x) * 8u;   // 4608 blocks, exact
    int isf = flag[0];
    uint32_t n = t / 768u;
    uint32_t d0 = t - n * 768u;
    u16x8 xv = *(const u16x8*)(xw + t);
    float v[8];
    #pragma unroll
    for (int q = 0; q < 8; q++) v[q] = b2f(xv[q]);
    if (n < SS) {
        f32x4 a0 = *(const f32x4*)(aggb + t);
        f32x4 a1 = *(const f32x4*)(aggb + t + 4);
        float dg = deg[n];
        #pragma unroll
        for (int q = 0; q < 4; q++) { v[q] = v[q] / dg + a0[q]; v[q + 4] = v[q + 4] / dg + a1[q]; }
    }
    float bb[8];
    if (isf) {
        f32x4 b0 = *(const f32x4*)((const float*)gcnb + d0);
        f32x4 b1 = *(const f32x4*)((const float*)gcnb + d0 + 4);
        #pragma unroll
        for (int q = 0; q < 4; q++) { bb[q] = b0[q]; bb[q + 4] = b1[q]; }
    } else {
        u16x8 b8 = *(const u16x8*)((const uint16_t*)gcnb + d0);
        #pragma unroll
        for (int q = 0; q < 8; q++) bb[q] = b2f(b8[q]);
    }
    u16x8 ov;
    #pragma unroll
    for (int q = 0; q < 8; q++) ov[q] = f2b(fmaxf(v[q] + bb[q], 0.f));
    *(u16x8*)(xw + t) = ov;
}

// ---------- colsum over first 128 rows ----------
__global__ __launch_bounds__(256) void k_colsum(const uint16_t* __restrict__ x,
                                                float* __restrict__ svec) {
    int d = blockIdx.x * 256 + threadIdx.x;
    if (d < DD) {
        float s = 0.f;
        for (int i = 0; i < SS; i++) s += b2f(x[(size_t)i * DD + d]);
        svec[d] = s;
    }
}

// ---------- mvec = svec @ ggc_W[l] ----------
__global__ __launch_bounds__(256) void k_matvec(const float* __restrict__ svec,
                                                const void* __restrict__ Wg, size_t ofs,
                                                float* __restrict__ mvec,
                                                const int* __restrict__ flag) {
    int k = blockIdx.x * 256 + threadIdx.x;
    int isf = flag[0];
    if (k < DD) {
        float s = 0.f;
        for (int d = 0; d < DD; d++) s += svec[d] * loadf(Wg, ofs + (size_t)d * DD + k, isf);
        mvec[k] = s;
    }
}

// ---------- giE = mvec @ wih.T + bih ----------
__global__ __launch_bounds__(256) void k_rowdot(const float* __restrict__ mvec,
                                                const void* __restrict__ wih,
                                                const void* __restrict__ bih,
                                                float* __restrict__ giE,
                                                const int* __restrict__ flag) {
    int rr = blockIdx.x, tid = threadIdx.x;
    int isf = flag[0];
    float s = 0.f;
    for (int k = tid; k < DD; k += 256) s += mvec[k] * loadf(wih, (size_t)rr * DD + k, isf);
    __shared__ float red[256];
    red[tid] = s; __syncthreads();
    for (int o = 128; o > 0; o >>= 1) { if (tid < o) red[tid] += red[tid + o]; __syncthreads(); }
    if (tid == 0) giE[rr] = red[0] + loadf(bih, rr, isf);
}

// ---------- y = h_feature + relu(x_g), batched all 3 chunks, vec x8 ----------
__global__ __launch_bounds__(256) void k_build_y(const void* __restrict__ hf,
                                                 const uint16_t* __restrict__ xg,
                                                 uint16_t* __restrict__ y,
                                                 const int* __restrict__ flag) {
    uint32_t t = (blockIdx.x * 256 + threadIdx.x) * 8u;   // 4608 blocks, exact TOTAL_ND
    int isf = flag[0];
    uint32_t u = t;
    if (u >= 2u * NBSD) u -= 2u * NBSD; else if (u >= NBSD) u -= NBSD;
    u16x8 xv = *(const u16x8*)(xg + t);
    float h[8];
    if (isf) {
        f32x4 h0 = *(const f32x4*)((const float*)hf + u);
        f32x4 h1 = *(const f32x4*)((const float*)hf + u + 4);
        #pragma unroll
        for (int q = 0; q < 4; q++) { h[q] = h0[q]; h[q + 4] = h1[q]; }
    } else {
        u16x8 h8 = *(const u16x8*)((const uint16_t*)hf + u);
        #pragma unroll
        for (int q = 0; q < 8; q++) h[q] = b2f(h8[q]);
    }
    u16x8 ov;
    #pragma unroll
    for (int q = 0; q < 8; q++) ov[q] = f2b(h[q] + fmaxf(b2f(xv[q]), 0.f));
    *(u16x8*)(y + t) = ov;
}

// ---------- LayerNorm (batched: 12288 rows, per-g weight select) ----------
__global__ __launch_bounds__(256) void k_ln(const uint16_t* __restrict__ tin,
                                            const void* g0, const void* b0,
                                            const void* g1, const void* b1,
                                            const void* g2, const void* b2,
                                            float* __restrict__ out,
                                            const int* __restrict__ flag) {
    int m = blockIdx.x, tid = threadIdx.x;
    int isf = flag[0];
    int gs = m >> 12;
    const void* gw = (gs == 0) ? g0 : (gs == 1) ? g1 : g2;
    const void* bw = (gs == 0) ? b0 : (gs == 1) ? b1 : b2;
    float v0 = b2f(tin[(size_t)m * DD + tid]);
    float v1 = b2f(tin[(size_t)m * DD + tid + 256]);
    float v2 = b2f(tin[(size_t)m * DD + tid + 512]);
    __shared__ float red[256];
    red[tid] = v0 + v1 + v2; __syncthreads();
    for (int o = 128; o > 0; o >>= 1) { if (tid < o) red[tid] += red[tid + o]; __syncthreads(); }
    float mu = red[0] * (1.f / 768.f);
    __syncthreads();
    float d0 = v0 - mu, d1 = v1 - mu, d2 = v2 - mu;
    red[tid] = d0 * d0 + d1 * d1 + d2 * d2; __syncthreads();
    for (int o = 128; o > 0; o >>= 1) { if (tid < o) red[tid] += red[tid + o]; __syncthreads(); }
    float rstd = rsqrtf(red[0] * (1.f / 768.f) + 1e-5f);
    out[(size_t)m * DD + tid]       = d0 * rstd * loadf(gw, tid, isf)       + loadf(bw, tid, isf);
    out[(size_t)m * DD + tid + 256] = d1 * rstd * loadf(gw, tid + 256, isf) + loadf(bw, tid + 256, isf);
    out[(size_t)m * DD + tid + 512] = d2 * rstd * loadf(gw, tid + 512, isf) + loadf(bw, tid + 512, isf);
}

// ---------- weight convert: hi/lo bf16 split, elementwise vec x4 ----------
__global__ __launch_bounds__(256) void k_cvt2(const void* __restrict__ src,
                                              uint16_t* __restrict__ dh,
                                              uint16_t* __restrict__ dl, int n,
                                              const int* __restrict__ flag) {
    int t = (blockIdx.x * 256 + threadIdx.x) * 4;   // exact cover
    int isf = flag[0];
    float v[4];
    if (isf) {
        f32x4 s = *(const f32x4*)((const float*)src + t);
        #pragma unroll
        for (int q = 0; q < 4; q++) v[q] = s[q];
    } else {
        u16x4 s = *(const u16x4*)((const uint16_t*)src + t);
        #pragma unroll
        for (int q = 0; q < 4; q++) v[q] = b2f(s[q]);
    }
    u16x4 hh, ll;
    #pragma unroll
    for (int q = 0; q < 4; q++) {
        uint16_t h = f2b(v[q]);
        hh[q] = h;
        ll[q] = f2b(v[q] - b2f(h));
    }
    *(u16x4*)(dh + t) = hh;
    *(u16x4*)(dl + t) = ll;
}

// ---------- weight convert: transpose + hi/lo split, 7 matrices batched ----------
// z=0: gcn_W -> gdst; z=1..6: head weights -> tail slots (W1g0,W2g0,W1g1,W2g1,W1g2,W2g2)
__global__ __launch_bounds__(256) void k_cvtT7(const void* s0, const void* s1,
                                               const void* s2, const void* s3,
                                               const void* s4, const void* s5,
                                               const void* s6,
                                               uint16_t* __restrict__ gdst,
                                               uint16_t* __restrict__ tail,
                                               const int* __restrict__ flag) {
    __shared__ float tile[64][65];
    int isf = flag[0];
    int z = blockIdx.z;
    const void* src = (z == 0) ? s0 : (z == 1) ? s1 : (z == 2) ? s2 :
                      (z == 3) ? s3 : (z == 4) ? s4 : (z == 5) ? s5 : s6;
    uint16_t* dh = (z == 0) ? gdst : tail + (size_t)(z - 1) * WSLOT;
    uint16_t* dl = dh + WMAT;
    int k0 = blockIdx.x * 64, n0 = blockIdx.y * 64;
    for (int t = threadIdx.x; t < 4096; t += 256) {
        int r = t >> 6, c = t & 63;
        tile[r][c] = loadf(src, (size_t)(k0 + r) * DD + n0 + c, isf);
    }
    __syncthreads();
    for (int base = 0; base < 4096; base += 512) {
        int t = base + threadIdx.x * 2;
        int r = t >> 6, c = t & 63;
        float va = tile[c][r], vb = tile[c + 1][r];
        uint16_t ha = f2b(va), hb = f2b(vb);
        size_t o = (size_t)(n0 + r) * DD + k0 + c;
        *(u16x2*)(dh + o) = (u16x2){ha, hb};
        *(u16x2*)(dl + o) = (u16x2){f2b(va - b2f(ha)), f2b(vb - b2f(hb))};
    }
}

// =============== MFMA GEMM: C[M,768] = A[M,768] @ BT^T, bf16 hi/lo combined ====
// BT layout: [768][768] row = output col n, col = k; lo residual at BT+WMAT.
// 128x128 tile, BK=32, 4 waves; both halves in ONE K-loop (A staged once).
// z-batched (aZ/bZ/cZ strides); default block order (no swizzle: measured better).
enum { EPI_NONE = 0, EPI_BIAS_RELU = 3, EPI_BIAS = 4 };

template<int EPI>
__global__ __launch_bounds__(256)
void k_mgemm(const uint16_t* __restrict__ A, uint32_t aZ,
             const uint16_t* __restrict__ BTh, uint32_t bZ,
             const void* bias0, const void* bias1, const void* bias2,
             uint16_t* __restrict__ C, uint32_t cZ,
             const int* __restrict__ flag) {
    __shared__ __align__(16) uint16_t As[128 * 32];
    __shared__ __align__(16) uint16_t Bs[2][128 * 32];
    const int isf = flag[0];
    const int tid = threadIdx.x, lane = tid & 63, wid = tid >> 6;
    const int wr = wid >> 1, wc = wid & 1;
    const int z = blockIdx.z;
    const uint16_t* Az = A + (size_t)z * aZ;
    const uint16_t* Bh = BTh + (size_t)z * bZ;
    const uint16_t* Bl = Bh + WMAT;
    uint16_t* Cz = C + (size_t)z * cZ;
    const void* bias = (z == 0) ? bias0 : (z == 1) ? bias1 : bias2;
    const int m0 = blockIdx.y * 128, n0 = blockIdx.x * 128;

    f32x4 acc[4][4];
    #pragma unroll
    for (int i = 0; i < 4; i++)
        #pragma unroll
        for (int j = 0; j < 4; j++) acc[i][j] = (f32x4){0.f, 0.f, 0.f, 0.f};

    for (int k0 = 0; k0 < DD; k0 += 32) {
        #pragma unroll
        for (int rd = 0; rd < 2; rd++) {
            int c = rd * 256 + tid;
            int r = c >> 2, g = c & 3;
            int gl = g ^ ((r >> 1) & 3);               // pre-swizzled source
            int dofs = (rd * 256 + wid * 64) * 8;
            gload16(Az + (size_t)(m0 + r) * DD + k0 + gl * 8, As + dofs);
            gload16(Bh + (size_t)(n0 + r) * DD + k0 + gl * 8, Bs[0] + dofs);
            if (isf) gload16(Bl + (size_t)(n0 + r) * DD + k0 + gl * 8, Bs[1] + dofs);
        }
        __syncthreads();
        bf16x8 af[4], bh4[4], bl4[4];
        #pragma unroll
        for (int i = 0; i < 4; i++) {
            int r = wr * 64 + i * 16 + (lane & 15);
            int g = (lane >> 4) ^ ((r >> 1) & 3);
            af[i] = *(const bf16x8*)(As + r * 32 + g * 8);
        }
        #pragma unroll
        for (int j = 0; j < 4; j++) {
            int r = wc * 64 + j * 16 + (lane & 15);
            int g = (lane >> 4) ^ ((r >> 1) & 3);
            bh4[j] = *(const bf16x8*)(Bs[0] + r * 32 + g * 8);
            if (isf) bl4[j] = *(const bf16x8*)(Bs[1] + r * 32 + g * 8);
        }
        #pragma unroll
        for (int i = 0; i < 4; i++)
            #pragma unroll
            for (int j = 0; j < 4; j++)
                acc[i][j] = __builtin_amdgcn_mfma_f32_16x16x32_bf16(af[i], bh4[j], acc[i][j], 0, 0, 0);
        if (isf) {
            #pragma unroll
            for (int i = 0; i < 4; i++)
                #pragma unroll
                for (int j = 0; j < 4; j++)
                    acc[i][j] = __builtin_amdgcn_mfma_f32_16x16x32_bf16(af[i], bl4[j], acc[i][j], 0, 0, 0);
        }
        __syncthreads();
    }
    // D layout: col = lane&15, row = (lane>>4)*4 + q
    #pragma unroll
    for (int i = 0; i < 4; i++) {
        #pragma unroll
        for (int j = 0; j < 4; j++) {
            int n = n0 + wc * 64 + j * 16 + (lane & 15);
            int mb = m0 + wr * 64 + i * 16 + ((lane >> 4) << 2);
            float bv = 0.f;
            if (EPI != EPI_NONE) bv = loadf(bias, n, isf);
            #pragma unroll
            for (int q = 0; q < 4; q++) {
                float v = acc[i][j][q];
                if (EPI == EPI_BIAS_RELU) v = fmaxf(v + bv, 0.f);
                else if (EPI == EPI_BIAS) v = v + bv;
                Cz[(size_t)(mb + q) * DD + n] = f2b(v);
            }
        }
    }
}

// =============== MFMA fused GRU layer: 3-gate GEMM (hi/lo combined) + cell ====
// M=128 x (3 gates x 64) per block, 4 waves of 64x32, grid (12,96).
// Per wave-phase: 48 MFMA vs 16 ds_read_b128 -> MFMA-dominated.
__global__ __launch_bounds__(256)
void k_grum(const uint16_t* __restrict__ X,
            const uint16_t* __restrict__ Wh, const uint16_t* __restrict__ Wl,
            const void* __restrict__ bih, const void* __restrict__ bhh,
            const float* __restrict__ giE, uint16_t* __restrict__ Xn,
            const int* __restrict__ flag) {
    __shared__ __align__(16) uint16_t As[128 * 32];
    __shared__ __align__(16) uint16_t Bs[3][2][64 * 32];
    const int isf = flag[0];
    const int tid = threadIdx.x, lane = tid & 63, wid = tid >> 6;
    const int wr = wid >> 1, wc = wid & 1;
    const int n0 = blockIdx.x * 64, m0 = blockIdx.y * 128;

    f32x4 acc[3][4][2];
    #pragma unroll
    for (int gg = 0; gg < 3; gg++)
        #pragma unroll
        for (int i = 0; i < 4; i++)
            #pragma unroll
            for (int j = 0; j < 2; j++) acc[gg][i][j] = (f32x4){0.f, 0.f, 0.f, 0.f};

    const int sr = tid >> 2, sg = tid & 3;           // B staging: 64 rows x 4 grps
    const int sgl = sg ^ ((sr >> 1) & 3);
    const int dofs = wid * 64 * 8;

    for (int k0 = 0; k0 < DD; k0 += 32) {
        // A: 128 rows x 4 groups = 512 chunks over 256 threads x 2
        #pragma unroll
        for (int rd = 0; rd < 2; rd++) {
            int c = rd * 256 + tid;
            int r = c >> 2, g = c & 3;
            int gl = g ^ ((r >> 1) & 3);
            gload16(X + (size_t)(m0 + r) * DD + k0 + gl * 8,
                    As + (rd * 256 + wid * 64) * 8);
        }
        #pragma unroll
        for (int gg = 0; gg < 3; gg++) {
            size_t bro = (size_t)(gg * DD + n0 + sr) * DD + k0 + sgl * 8;
            gload16(Wh + bro, Bs[gg][0] + dofs);
            if (isf) gload16(Wl + bro, Bs[gg][1] + dofs);
        }
        __syncthreads();
        bf16x8 af[4];
        #pragma unroll
        for (int i = 0; i < 4; i++) {
            int r = wr * 64 + i * 16 + (lane & 15);
            int g = (lane >> 4) ^ ((r >> 1) & 3);
            af[i] = *(const bf16x8*)(As + r * 32 + g * 8);
        }
        #pragma unroll
        for (int gg = 0; gg < 3; gg++) {
            bf16x8 bh2[2], bl2[2];
            #pragma unroll
            for (int j = 0; j < 2; j++) {
                int r = wc * 32 + j * 16 + (lane & 15);
                int g = (lane >> 4) ^ ((r >> 1) & 3);
                bh2[j] = *(const bf16x8*)(Bs[gg][0] + r * 32 + g * 8);
                if (isf) bl2[j] = *(const bf16x8*)(Bs[gg][1] + r * 32 + g * 8);
            }
            #pragma unroll
            for (int j = 0; j < 2; j++)
                #pragma unroll
                for (int i = 0; i < 4; i++)
                    acc[gg][i][j] = __builtin_amdgcn_mfma_f32_16x16x32_bf16(af[i], bh2[j], acc[gg][i][j], 0, 0, 0);
            if (isf) {
                #pragma unroll
                for (int j = 0; j < 2; j++)
                    #pragma unroll
                    for (int i = 0; i < 4; i++)
                        acc[gg][i][j] = __builtin_amdgcn_mfma_f32_16x16x32_bf16(af[i], bl2[j], acc[gg][i][j], 0, 0, 0);
            }
        }
        __syncthreads();
    }
    // epilogue: full GRU cell pointwise
    #pragma unroll
    for (int j = 0; j < 2; j++) {
        int n = n0 + wc * 32 + j * 16 + (lane & 15);
        float bh0 = loadf(bhh, n, isf);
        float bh1 = loadf(bhh, DD + n, isf);
        float bh2v = loadf(bhh, 2 * DD + n, isf);
        float gE0 = giE[n], gE1 = giE[DD + n], gE2 = giE[2 * DD + n];
        float bi0 = loadf(bih, n, isf);
        float bi1 = loadf(bih, DD + n, isf);
        float bi2 = loadf(bih, 2 * DD + n, isf);
        #pragma unroll
        for (int i = 0; i < 4; i++) {
            int mb = m0 + wr * 64 + i * 16 + ((lane >> 4) << 2);
            #pragma unroll
            for (int q = 0; q < 4; q++) {
                int m = mb + q;
                bool msg = (m < SS);
                float gr = msg ? gE0 : bi0;
                float gz = msg ? gE1 : bi1;
                float gn = msg ? gE2 : bi2;
                float rg = 1.f / (1.f + expf(-(acc[0][i][j][q] + bh0 + gr)));
                float zg = 1.f / (1.f + expf(-(acc[1][i][j][q] + bh1 + gz)));
                float hn = acc[2][i][j][q] + bh2v;
                float nn = tanhf(gn + rg * hn);
                float xo = b2f(X[(size_t)m * DD + n]);
                Xn[(size_t)m * DD + n] = f2b((1.f - zg) * nn + zg * xo);
            }
        }
    }
}

// ============================== driver ==============================
extern "C" void kernel_launch(void* const* d_in, const int* in_sizes, int n_in,
                              void* d_out, int out_size, void* d_ws, size_t ws_size,
                              hipStream_t stream) {
    float* OUTF = (float*)d_out;            // FINAL output: fp32
    uint16_t* OB = (uint16_t*)d_out;        // first 18.9MB of d_out as bf16 trunk/H scratch

    static const int expect[29] = {
        3145728,3145728,3145728,3145728, 589824,768, 1179648, 1769472,1769472, 2304,2304,
        589824,768,589824,768,768,768,
        589824,768,589824,768,768,768,
        589824,768,589824,768,768,768 };
    int bad = -1;
    if (n_in != 29) bad = 90;
    else { for (int i = 0; i < 29; i++) if (in_sizes[i] != expect[i]) { bad = i; break; } }
    if (bad < 0 && out_size != (int)TOTAL_ND) bad = 91;
    if (bad < 0 && ws_size < 33ull * 1024 * 1024) bad = 92;
    if (bad >= 0) {
        k_diag<<<1, 64, 0, stream>>>(OUTF, 10000.f + 100.f * (float)bad);
        return;
    }

    // ws layout (floats): small scratch | F128 hi/lo | W0 | WH | WT  (~30.8 MiB)
    float* fbase = (float*)d_ws;
    float* simb = fbase;                        // 16384
    float* mnmx = simb + 16384;                 // 2
    float* deg  = mnmx + 2;                     // 128
    float* dinv = deg + 128;                    // 128
    float* aggb = dinv + 128;                   // 98304
    float* svec = aggb + 98304;                 // 768
    float* mvec = svec + 768;                   // 768
    float* giE  = mvec + 768;                   // 2304
    int*   flag = (int*)(giE + 2304);           // 1
    uint16_t* F128h = (uint16_t*)(fbase + 118916);  // 98304 u16
    uint16_t* F128l = (uint16_t*)(fbase + 168068);  // 98304 u16
    uint16_t* W0 = (uint16_t*)(fbase + 217220);     // 9,437,184 u16
    uint16_t* WH = W0 + TOTAL_ND;                   // 3,145,728 u16 slots
    uint16_t* WT = WH + NBSD;                       // 3,145,728 u16 slots

    // head weights hi/lo live in the TAIL of d_out (last 13.5 MB; dead before LN)
    uint16_t* tailW = (uint16_t*)((char*)d_out + 23592960);  // 6 slots x WSLOT

    const void* hf = d_in[0];
    const void* hc = d_in[1];
    const void* hd = d_in[2];
    const void* hs = d_in[3];

    k_probe<<<1, 64, 0, stream>>>(hf, flag);

    // ---- all transpose-weight conversions batched (gcn_W -> WH, heads -> tail) ----
    k_cvtT7<<<dim3(12, 12, 7), 256, 0, stream>>>(
        d_in[4], d_in[11], d_in[13], d_in[17], d_in[19], d_in[23], d_in[25],
        WH, tailW, flag);

    // ---- GCN front-end ----
    k_build_feats<<<3072, 256, 0, stream>>>(hc, hd, hs, W0, flag);
    k_build_f128<<<384, 256, 0, stream>>>(hc, hd, hs, F128h, F128l, flag);
    k_simgemm<<<dim3(2, 2), 256, 0, stream>>>(F128h, F128l, simb);
    k_simpost<<<1, 256, 0, stream>>>(simb, mnmx);
    k_deg<<<SS, SS, 0, stream>>>(simb, mnmx, deg, dinv);
    k_mgemm<EPI_NONE><<<dim3(6, 96, 1), 256, 0, stream>>>(
        W0, 0, WH, 0, nullptr, nullptr, nullptr, OB, 0, flag);
    k_agg<<<dim3(SS, 3), 256, 0, stream>>>(simb, dinv, OB, aggb);
    k_gcn_combine<<<4608, 256, 0, stream>>>(OB, aggb, deg, d_in[5], flag);

    // ---- GatedGraphConv: whh hi->WH, lo->WT (gcn_W in WH now dead) ----
    k_cvt2<<<1728, 256, 0, stream>>>(d_in[8], WH, WT, 1769472, flag);

    k_colsum<<<3, 256, 0, stream>>>(OB, svec);
    k_matvec<<<3, 256, 0, stream>>>(svec, d_in[6], 0, mvec, flag);
    k_rowdot<<<2304, 256, 0, stream>>>(mvec, d_in[7], d_in[9], giE, flag);
    k_grum<<<dim3(12, 96), 256, 0, stream>>>(OB, WH, WT, d_in[9], d_in[10], giE, W0, flag);

    k_colsum<<<3, 256, 0, stream>>>(W0, svec);
    k_matvec<<<3, 256, 0, stream>>>(svec, d_in[6], (size_t)DD * DD, mvec, flag);
    k_rowdot<<<2304, 256, 0, stream>>>(mvec, d_in[7], d_in[9], giE, flag);
    k_grum<<<dim3(12, 96), 256, 0, stream>>>(W0, WH, WT, d_in[9], d_in[10], giE, OB, flag);

    // ---- y = hf + relu(x) for all 3 chunks (OB -> W0); OB then dead ----
    k_build_y<<<4608, 256, 0, stream>>>(hf, OB, W0, flag);

    // ---- heads batched over z: y(W0) -> H(OB) -> T(W0) -> LN(d_out) ----
    k_mgemm<EPI_BIAS_RELU><<<dim3(6, 32, 3), 256, 0, stream>>>(
        W0, NBSD, tailW, 2 * WSLOT, d_in[12], d_in[18], d_in[24], OB, NBSD, flag);
    k_mgemm<EPI_BIAS><<<dim3(6, 32, 3), 256, 0, stream>>>(
        OB, NBSD, tailW + WSLOT, 2 * WSLOT, d_in[14], d_in[20], d_in[26], W0, NBSD, flag);
    k_ln<<<NNODE, 256, 0, stream>>>(W0, d_in[15], d_in[16], d_in[21], d_in[22],
                                    d_in[27], d_in[28], OUTF, flag);
}